// Round 1
// baseline (1961.662 us; speedup 1.0000x reference)
//
#include <hip/hip_runtime.h>
#include <hip/hip_bf16.h>

using bf16 = __hip_bfloat16;

#define LN_EPS 1e-5f

__device__ __forceinline__ float bf2f(unsigned short b) {
    return __uint_as_float(((unsigned int)b) << 16);
}
__device__ __forceinline__ unsigned short f2bf_bits(float f) {
    __hip_bfloat16 h = __float2bfloat16(f);
    return *reinterpret_cast<unsigned short*>(&h);
}
__device__ __forceinline__ float cvt_to_f(float v){ return v; }
__device__ __forceinline__ float cvt_to_f(bf16 v){ return __bfloat162float(v); }

__device__ __forceinline__ void load4f(const float* p, float v[4]) {
    float4 t = *reinterpret_cast<const float4*>(p);
    v[0]=t.x; v[1]=t.y; v[2]=t.z; v[3]=t.w;
}
__device__ __forceinline__ void load4f(const bf16* p, float v[4]) {
    ushort4 t = *reinterpret_cast<const ushort4*>(p);
    v[0]=bf2f(t.x); v[1]=bf2f(t.y); v[2]=bf2f(t.z); v[3]=bf2f(t.w);
}
__device__ __forceinline__ void store4f(float* p, const float v[4]) {
    *reinterpret_cast<float4*>(p) = make_float4(v[0],v[1],v[2],v[3]);
}
__device__ __forceinline__ void store4f(bf16* p, const float v[4]) {
    ushort4 u; u.x=f2bf_bits(v[0]); u.y=f2bf_bits(v[1]); u.z=f2bf_bits(v[2]); u.w=f2bf_bits(v[3]);
    *reinterpret_cast<ushort4*>(p) = u;
}
__device__ __forceinline__ void store1f(float* p, float v){ *p = v; }
__device__ __forceinline__ void store1f(bf16* p, float v){ *p = __float2bfloat16(v); }

// ---------------- LayerNorm row stats (mean, 1/sqrt(var+eps)) ----------------
__global__ __launch_bounds__(256) void ln_stats_kernel(const float* __restrict__ x,
        float* __restrict__ mu_o, float* __restrict__ rstd_o, int rows, int n) {
    int wave = threadIdx.x >> 6;
    int lane = threadIdx.x & 63;
    int row = blockIdx.x * 4 + wave;
    if (row >= rows) return;
    const float* xr = x + (long)row * n;
    float s = 0.f, ss = 0.f;
    for (int i = lane; i < n; i += 64) { float v = xr[i]; s += v; ss += v*v; }
    #pragma unroll
    for (int off = 32; off; off >>= 1) { s += __shfl_down(s, off); ss += __shfl_down(ss, off); }
    if (lane == 0) {
        float mu = s / n;
        float var = ss / n - mu*mu;
        mu_o[row] = mu;
        rstd_o[row] = 1.f / sqrtf(var + LN_EPS);
    }
}

// ---------------- generic tiled f32 GEMM (64x64 tile, BK=16, 4x4/thread) ----------------
// C[m][n] = epilogue( sum_k A[m][k] * B(k,n) )
// BT=1: B(k,n) = B[n*ldb + k]  (both operands k-contiguous, "NT")
// BT=0: B(k,n) = B[k*ldb + n]  ("NN")
// ALN=1: A element is layernormed on the fly: (a - mu[m])*rstd[m]*lng[k] + lnb[k]
// EPI: 0 = relu(acc + bias[n])             (h1, bf16 out)
//      1 = acc + bias[n] + resid[m][n]     (x1, f32 out)
//      2 = ((acc + bias[m]) - bm[m]) * (g[m]/sqrt(bv[m]+eps)) + bb[m]   (conv+bn)
//      3 = acc + bias[m]                   (cp)
template<typename TA, typename TB, typename TO, int BT, int ALN, int EPI>
__global__ __launch_bounds__(256) void gemm_tile(
    const TA* __restrict__ A, long lda, long sA,
    const TB* __restrict__ Bm, long ldb, long sB,
    TO* __restrict__ Cm, long ldc, long sC,
    int M, int N, int K,
    const float* __restrict__ bias,
    const float* __restrict__ g, const float* __restrict__ bb,
    const float* __restrict__ bm, const float* __restrict__ bv,
    const float* __restrict__ resid, long ldres,
    const float* __restrict__ mu, const float* __restrict__ rstd,
    const float* __restrict__ lng, const float* __restrict__ lnb)
{
    __shared__ float As[16][64];
    __shared__ float Bs[16][64];
    const int bz = blockIdx.z;
    const TA* Ab = A + (long)bz * sA;
    const TB* Bb = Bm + (long)bz * sB;
    TO* Cb = Cm + (long)bz * sC;
    const int m0 = blockIdx.y * 64;
    const int n0 = blockIdx.x * 64;
    const int tid = threadIdx.x;
    const int tx = tid & 15, ty = tid >> 4;
    const int arow = tid >> 2, akq = tid & 3;

    float acc[4][4] = {};

    for (int k0 = 0; k0 < K; k0 += 16) {
        // A tile -> As[k][m] (transpose-stage)
        {
            float v[4];
            int m = m0 + arow;
            if (m < M) {
                load4f(Ab + (long)m*lda + k0 + akq*4, v);
                if (ALN) {
                    float mm = mu[m], rs = rstd[m];
                    #pragma unroll
                    for (int j=0;j<4;j++) {
                        int k = k0 + akq*4 + j;
                        v[j] = (v[j]-mm)*rs*lng[k] + lnb[k];
                    }
                }
            } else { v[0]=v[1]=v[2]=v[3]=0.f; }
            #pragma unroll
            for (int j=0;j<4;j++) As[akq*4+j][arow] = v[j];
        }
        // B tile -> Bs[k][n]
        if (BT) {
            float v[4];
            int col = n0 + arow;
            if (col < N) load4f(Bb + (long)col*ldb + k0 + akq*4, v);
            else { v[0]=v[1]=v[2]=v[3]=0.f; }
            #pragma unroll
            for (int j=0;j<4;j++) Bs[akq*4+j][arow] = v[j];
        } else {
            int kk = tid >> 4;
            int nq = tid & 15;
            int col = n0 + nq*4;
            float v[4];
            const TB* p = Bb + (long)(k0+kk)*ldb + col;
            if (col + 3 < N) load4f(p, v);
            else {
                #pragma unroll
                for (int j=0;j<4;j++) v[j] = (col+j < N) ? cvt_to_f(p[j]) : 0.f;
            }
            *reinterpret_cast<float4*>(&Bs[kk][nq*4]) = make_float4(v[0],v[1],v[2],v[3]);
        }
        __syncthreads();
        #pragma unroll
        for (int kk=0; kk<16; kk++) {
            float a[4], b[4];
            *reinterpret_cast<float4*>(a) = *reinterpret_cast<const float4*>(&As[kk][ty*4]);
            *reinterpret_cast<float4*>(b) = *reinterpret_cast<const float4*>(&Bs[kk][tx*4]);
            #pragma unroll
            for (int i=0;i<4;i++)
                #pragma unroll
                for (int j=0;j<4;j++)
                    acc[i][j] = fmaf(a[i], b[j], acc[i][j]);
        }
        __syncthreads();
    }
    // epilogue
    #pragma unroll
    for (int i=0;i<4;i++) {
        int m = m0 + ty*4 + i;
        if (m >= M) continue;
        float rb = 0.f, bninv = 1.f, bnmv = 0.f, bnbv = 0.f;
        if (EPI == 2) { rb = bias[m]; bninv = g[m]/sqrtf(bv[m]+LN_EPS); bnmv = bm[m]; bnbv = bb[m]; }
        if (EPI == 3) { rb = bias[m]; }
        float vout[4];
        int nn0 = n0 + tx*4;
        #pragma unroll
        for (int j=0;j<4;j++) {
            int nn = nn0 + j;
            float t = acc[i][j];
            if (nn < N) {
                if (EPI == 0)      { t += bias[nn]; t = fmaxf(t, 0.f); }
                else if (EPI == 1) { t += bias[nn]; t += resid[(long)m*ldres + nn]; }
                else if (EPI == 2) { float t2 = t + rb; t = (t2 - bnmv)*bninv + bnbv; }
                else               { t += rb; }
            }
            vout[j] = t;
        }
        TO* cp_ = Cb + (long)m*ldc + nn0;
        if (nn0 + 3 < N) store4f(cp_, vout);
        else {
            #pragma unroll
            for (int j=0;j<4;j++) if (nn0+j < N) store1f(cp_+j, vout[j]);
        }
    }
}

// ---------------- LIF over time axis n (last dim of x[b][c][n]) -> s[n][c][b] ----------------
__global__ __launch_bounds__(256) void lif1_kernel(const float* __restrict__ x,
        bf16* __restrict__ s, int C_, int N_) {
    int t = blockIdx.x * 256 + threadIdx.x;
    int b = t & 63;
    int c = t >> 6;
    if (c >= C_) return;
    const float* xr = x + ((long)b*C_ + c) * N_;
    bf16* sp = s + (long)c*64 + b;
    const long sn = (long)C_*64;
    float v = 0.f;
    float4 cur = *reinterpret_cast<const float4*>(xr);
    for (int n = 0; n < N_; n += 4) {
        float4 nxt = cur;
        if (n + 4 < N_) nxt = *reinterpret_cast<const float4*>(xr + n + 4);
        float xa[4] = {cur.x, cur.y, cur.z, cur.w};
        #pragma unroll
        for (int j=0;j<4;j++) {
            v = v + (xa[j] - v)*0.5f;   // v += (x-v)/tau, tau=2 (exact halving)
            bool sk = (v >= 1.0f);
            sp[(long)(n+j)*sn] = __float2bfloat16(sk ? 1.f : 0.f);
            if (sk) v = 0.f;
        }
        cur = nxt;
    }
}

// ---------------- LIF over time axis n of y[n][o][b] (rows = o*64+b), depth-8 prefetch ----------------
__global__ __launch_bounds__(256) void lif2_kernel(const float* __restrict__ y,
        bf16* __restrict__ s2, int rows, int N_) {
    int idx = blockIdx.x * 256 + threadIdx.x;
    if (idx >= rows) return;
    const long st = rows;
    const float* yp = y + idx;
    float buf[8];
    #pragma unroll
    for (int j=0;j<8;j++) buf[j] = yp[(long)j*st];
    float v = 0.f;
    for (int n0 = 0; n0 < N_; n0 += 8) {
        #pragma unroll
        for (int j=0;j<8;j++) {
            float cur = buf[j];
            int np = n0 + j + 8;
            if (np < N_) buf[j] = yp[(long)np*st];
            v = v + (cur - v)*0.5f;
            bool sk = (v >= 1.0f);
            s2[(long)(n0+j)*st + idx] = __float2bfloat16(sk ? 1.f : 0.f);
            if (sk) v = 0.f;
        }
    }
}

// ---------------- x1[b][c][n] += z[n][c][b]  (LDS-tiled (n,b) transpose per c) ----------------
__global__ __launch_bounds__(256) void transpose_add_kernel(float* __restrict__ x1,
        const bf16* __restrict__ z, int C_, int N_) {
    __shared__ float tile[64][65];
    int c = blockIdx.x;
    int n0 = blockIdx.y * 64;
    int lane = threadIdx.x & 63;
    int wv = threadIdx.x >> 6;
    #pragma unroll
    for (int i = 0; i < 16; i++) {
        int nn = wv*16 + i;
        int n = n0 + nn;
        float v = 0.f;
        if (n < N_) v = __bfloat162float(z[(long)n*(C_*64) + (long)c*64 + lane]);
        tile[nn][lane] = v;
    }
    __syncthreads();
    #pragma unroll
    for (int i = 0; i < 16; i++) {
        int b = wv*16 + i;
        int n = n0 + lane;
        if (n < N_) {
            long off = ((long)b*C_ + c)*N_ + n;
            x1[off] += tile[lane][b];
        }
    }
}

// ---------------- rp GEMM (K=400, R=4) + per-row L2 normalize; one block per b ----------------
__global__ __launch_bounds__(512) void rp_norm_kernel(const float* __restrict__ xc,
        const float* __restrict__ rpw, const float* __restrict__ rpb,
        float* __restrict__ out, int N_) {
    __shared__ float wr[4*400];
    __shared__ float red[8];
    int b = blockIdx.x;
    int o = threadIdx.x;            // 0..511
    for (int i = threadIdx.x; i < 4*400; i += 512) wr[i] = rpw[i];
    __syncthreads();
    const float* row = xc + ((long)b*512 + o)*N_;
    float acc[4] = {rpb[0], rpb[1], rpb[2], rpb[3]};
    for (int n = 0; n < N_; n += 4) {
        float4 xv = *reinterpret_cast<const float4*>(row + n);
        #pragma unroll
        for (int r=0;r<4;r++) {
            acc[r] = fmaf(xv.x, wr[r*400+n  ], acc[r]);
            acc[r] = fmaf(xv.y, wr[r*400+n+1], acc[r]);
            acc[r] = fmaf(xv.z, wr[r*400+n+2], acc[r]);
            acc[r] = fmaf(xv.w, wr[r*400+n+3], acc[r]);
        }
    }
    float sq = acc[0]*acc[0]+acc[1]*acc[1]+acc[2]*acc[2]+acc[3]*acc[3];
    #pragma unroll
    for (int off=32; off; off>>=1) sq += __shfl_down(sq, off);
    if ((threadIdx.x & 63) == 0) red[threadIdx.x>>6] = sq;
    __syncthreads();
    if (threadIdx.x == 0) {
        float s = 0.f;
        #pragma unroll
        for (int i=0;i<8;i++) s += red[i];
        red[0] = fmaxf(sqrtf(s), 1e-12f);
    }
    __syncthreads();
    float nrm = red[0];
    float4 ov = make_float4(acc[0]/nrm, acc[1]/nrm, acc[2]/nrm, acc[3]/nrm);
    *reinterpret_cast<float4*>(out + (long)b*2048 + o*4) = ov;
}

extern "C" void kernel_launch(void* const* d_in, const int* in_sizes, int n_in,
                              void* d_out, int out_size, void* d_ws, size_t ws_size,
                              hipStream_t stream) {
    const float* x    = (const float*)d_in[0];
    const float* ln_g = (const float*)d_in[1];
    const float* ln_b = (const float*)d_in[2];
    const float* w1   = (const float*)d_in[3];
    const float* b1   = (const float*)d_in[4];
    const float* w2   = (const float*)d_in[5];
    const float* b2   = (const float*)d_in[6];
    const float* c1w  = (const float*)d_in[7];
    const float* c1b  = (const float*)d_in[8];
    const float* bn1g = (const float*)d_in[9];
    const float* bn1b = (const float*)d_in[10];
    const float* bn1m = (const float*)d_in[11];
    const float* bn1v = (const float*)d_in[12];
    const float* c2w  = (const float*)d_in[13];
    const float* c2b  = (const float*)d_in[14];
    const float* bn2g = (const float*)d_in[15];
    const float* bn2b = (const float*)d_in[16];
    const float* bn2m = (const float*)d_in[17];
    const float* bn2v = (const float*)d_in[18];
    const float* cpw  = (const float*)d_in[19];
    const float* cpb  = (const float*)d_in[20];
    const float* rpw  = (const float*)d_in[21];
    const float* rpb  = (const float*)d_in[22];

    const int B = 64, C = 1024, N = 400, OC = 512;
    const int RC = B*C;               // 65536 rows (b,c)
    const int OB = N*B;               // 25600 rows (o,b) of LIF2

    char* ws = (char*)d_ws;
    size_t off = 0;
    auto alloc = [&](size_t bytes){ size_t o = off; off += (bytes + 255) & ~(size_t)255; return o; };
    float* mu   = (float*)(ws + alloc((size_t)RC*4));
    float* rstd = (float*)(ws + alloc((size_t)RC*4));
    float* x1   = (float*)(ws + alloc((size_t)RC*N*4));     // x + MLP out; later += z^T in place
    float* y    = (float*)(ws + alloc((size_t)N*N*B*4));    // conv1+bn1 out [n][o][b]
    bf16*  s2   = (bf16*) (ws + alloc((size_t)N*N*B*2));    // LIF2 spikes [n][o][b]
    char*  hz   =          ws + alloc((size_t)RC*N*2);      // h1 (bf16), then z (bf16) [n][c][b]
    char*  sxc  =          ws + alloc((size_t)RC*N*2 > (size_t)B*OC*N*4 ? (size_t)RC*N*2 : (size_t)B*OC*N*4);
    bf16*  h1   = (bf16*)hz;
    bf16*  z    = (bf16*)hz;
    bf16*  s    = (bf16*)sxc;   // LIF1 spikes [n][c][b]
    float* xc   = (float*)sxc;  // cp out [b][o][n] (reuses s region)

    // 1) LN stats
    ln_stats_kernel<<<dim3(RC/4), dim3(256), 0, stream>>>(x, mu, rstd, RC, N);

    // 2) h1 = relu(LN(x) @ w1^T + b1)   [RC x 400] bf16
    gemm_tile<float,float,bf16,1,1,0><<<dim3(7,1024,1), dim3(256), 0, stream>>>(
        x, N, 0, w1, N, 0, h1, N, 0, RC, N, N,
        b1, nullptr,nullptr,nullptr,nullptr, nullptr,0, mu, rstd, ln_g, ln_b);

    // 3) x1 = x + h1 @ w2^T + b2        [RC x 400] f32
    gemm_tile<bf16,float,float,1,0,1><<<dim3(7,1024,1), dim3(256), 0, stream>>>(
        h1, N, 0, w2, N, 0, x1, N, 0, RC, N, N,
        b2, nullptr,nullptr,nullptr,nullptr, x, N, nullptr,nullptr,nullptr,nullptr);

    // 4) LIF1: x[b][c][n] -> s[n][c][b]
    lif1_kernel<<<dim3(RC/256), dim3(256), 0, stream>>>(x, s, C, N);

    // 5) conv1 + bn1: y[n] = bn1(c1w @ s[n] + c1b)   batch n=400, M=400,N=64,K=1024
    gemm_tile<float,bf16,float,0,0,2><<<dim3(1,7,400), dim3(256), 0, stream>>>(
        c1w, C, 0, s, B, (long)C*B, y, B, (long)N*B, N, B, C,
        c1b, bn1g, bn1b, bn1m, bn1v, nullptr,0, nullptr,nullptr,nullptr,nullptr);

    // 6) LIF2: y -> s2
    lif2_kernel<<<dim3((OB+255)/256), dim3(256), 0, stream>>>(y, s2, OB, N);

    // 7) conv2 + bn2: z[n] = bn2(c2w @ s2[n] + c2b)  batch n=400, M=1024,N=64,K=400
    gemm_tile<float,bf16,bf16,0,0,2><<<dim3(1,16,400), dim3(256), 0, stream>>>(
        c2w, N, 0, s2, B, (long)N*B, z, B, (long)C*B, C, B, N,
        c2b, bn2g, bn2b, bn2m, bn2v, nullptr,0, nullptr,nullptr,nullptr,nullptr);

    // 8) x1 += z^T  (in place)
    transpose_add_kernel<<<dim3(C,7), dim3(256), 0, stream>>>(x1, z, C, N);

    // 9) cp: xc[b] = cpw @ x1[b] + cpb   batch b=64, M=512,N=400,K=1024
    gemm_tile<float,float,float,0,0,3><<<dim3(7,8,64), dim3(256), 0, stream>>>(
        cpw, C, 0, x1, N, (long)C*N, xc, N, (long)OC*N, OC, N, C,
        cpb, nullptr,nullptr,nullptr,nullptr, nullptr,0, nullptr,nullptr,nullptr,nullptr);

    // 10) rp + L2 normalize -> d_out [64][2048]
    rp_norm_kernel<<<dim3(B), dim3(512), 0, stream>>>(xc, rpw, rpb, (float*)d_out, N);
}

// Round 2
// 718.658 us; speedup vs baseline: 2.7296x; 2.7296x over previous
//
#include <hip/hip_runtime.h>
#include <hip/hip_bf16.h>

typedef __attribute__((ext_vector_type(8))) short s8v;
typedef __attribute__((ext_vector_type(4))) float f32x4;
using bf16 = __hip_bfloat16;

#define LN_EPS 1e-5f

__device__ __forceinline__ float bf2f(unsigned short b){ return __uint_as_float(((unsigned)b)<<16); }
__device__ __forceinline__ unsigned short f2bf(float f){ __hip_bfloat16 h = __float2bfloat16(f); return *reinterpret_cast<unsigned short*>(&h); }

// MFMA k-half permutation: stored position of true k within each 32-k block.
// frag ds_read_b128 at stored bytes [16g..16g+15] must deliver k={4g..4g+3, 16+4g..16+4g+3}.
__device__ __forceinline__ int posk(int k){
    int q = (k >> 2) & 7;
    int s = (q < 4) ? (2*q) : (2*q - 7);
    return (k & ~31) | (s << 2) | (k & 3);
}

__device__ __forceinline__ void async16(const void* g, void* l){
    __builtin_amdgcn_global_load_lds(
        (const __attribute__((address_space(1))) unsigned int*)g,
        (__attribute__((address_space(3))) unsigned int*)l, 16, 0, 0);
}

// ---------------- fused LayerNorm -> padded+permuted bf16 A-matrix ----------------
// x[row=(b,c)][0..399] f32 -> xln[row][448] bf16 (cols 400..447 = 0), cols posk-permuted
__global__ __launch_bounds__(256) void ln_fused(const float* __restrict__ x,
        const float* __restrict__ g, const float* __restrict__ b,
        unsigned short* __restrict__ xln)
{
    int lane = threadIdx.x & 63, wv = threadIdx.x >> 6;
    long row = (long)blockIdx.x * 4 + wv;
    const float* xr = x + row * 400;
    float v[7];
    float s = 0.f, ss = 0.f;
    #pragma unroll
    for (int i = 0; i < 7; ++i) {
        int n = lane + i * 64;
        float t = (n < 400) ? xr[n] : 0.f;
        v[i] = t; s += t; ss += t * t;
    }
    #pragma unroll
    for (int o = 32; o; o >>= 1) { s += __shfl_down(s, o); ss += __shfl_down(ss, o); }
    s = __shfl(s, 0); ss = __shfl(ss, 0);
    float mu = s * 0.0025f;
    float rstd = rsqrtf(ss * 0.0025f - mu * mu + LN_EPS);
    unsigned short* orow = xln + row * 448;
    #pragma unroll
    for (int i = 0; i < 7; ++i) {
        int n = lane + i * 64;
        float t = (n < 400) ? ((v[i] - mu) * rstd * g[n] + b[n]) : 0.f;
        orow[posk(n)] = f2bf(t);
    }
}

// ---------------- x[b][c][n] -> xT[b][n][c] f32 ----------------
__global__ __launch_bounds__(256) void transpose_x(const float* __restrict__ x, float* __restrict__ xT)
{
    __shared__ float tile[64][65];
    int b = blockIdx.z, n0 = blockIdx.y * 64, c0 = blockIdx.x * 64;
    int lane = threadIdx.x & 63, wv = threadIdx.x >> 6;
    int n = n0 + lane;
    #pragma unroll
    for (int q = 0; q < 16; ++q) {
        int cc = wv * 16 + q;
        tile[cc][lane] = (n < 400) ? x[((long)b * 1024 + c0 + cc) * 400 + n] : 0.f;
    }
    __syncthreads();
    #pragma unroll
    for (int q = 0; q < 16; ++q) {
        int nn = wv * 16 + q;
        if (n0 + nn < 400)
            xT[((long)b * 400 + n0 + nn) * 1024 + c0 + lane] = tile[lane][nn];
    }
}

// ---------------- weight prep: pad + posk-permute + optional hi/lo split along K ----------------
// dst[r][posk(k)]; if khalf: k<khalf -> bf16_hi(src[r][k]), k>=khalf -> bf16_lo(src[r][k-khalf])
__global__ void prep_w(const float* __restrict__ src, int R0, int K0,
                       unsigned short* __restrict__ dst, int K2, int khalf)
{
    int k = blockIdx.x * 256 + threadIdx.x;
    if (k >= K2) return;
    int r = blockIdx.y;
    int ks = k, half = 0;
    if (khalf && k >= khalf) { ks = k - khalf; half = 1; }
    float v = 0.f;
    if (r < R0 && ks < K0) v = src[(long)r * K0 + ks];
    unsigned short out;
    if (!khalf) out = f2bf(v);
    else {
        float hi = bf2f(f2bf(v));
        out = half ? f2bf(v - hi) : f2bf(hi);
    }
    dst[(long)r * K2 + posk(k)] = out;
}

// ---------------- param prep: padded biases + folded bn scale/shift ----------------
__global__ void prep_params(
    const float* __restrict__ b1, const float* __restrict__ b2,
    const float* __restrict__ c1b, const float* __restrict__ g1, const float* __restrict__ bb1,
    const float* __restrict__ m1, const float* __restrict__ v1,
    const float* __restrict__ c2b, const float* __restrict__ g2, const float* __restrict__ bb2,
    const float* __restrict__ m2, const float* __restrict__ v2,
    float* __restrict__ b1p, float* __restrict__ b2p,
    float* __restrict__ sc1, float* __restrict__ sh1,
    float* __restrict__ sc2, float* __restrict__ sh2)
{
    int t = threadIdx.x;
    if (t < 512) {
        b1p[t] = (t < 400) ? b1[t] : 0.f;
        b2p[t] = (t < 400) ? b2[t] : 0.f;
        float sc = 0.f, sh = 0.f;
        if (t < 400) { sc = g1[t] / sqrtf(v1[t] + LN_EPS); sh = (c1b[t] - m1[t]) * sc + bb1[t]; }
        sc1[t] = sc; sh1[t] = sh;
    }
    float sc = g2[t] / sqrtf(v2[t] + LN_EPS);
    sc2[t] = sc;
    sh2[t] = (c2b[t] - m2[t]) * sc + bb2[t];
}

// ---------------- LIF1: x[b][c][n] -> s[(n*64+b)][posk(c)] bf16 spikes ----------------
__global__ __launch_bounds__(256) void lif1(const float* __restrict__ x, unsigned short* __restrict__ s)
{
    int c = blockIdx.x * 256 + threadIdx.x;
    int b = blockIdx.y;
    const float* xr = x + ((long)b * 1024 + c) * 400;
    unsigned short* sp = s + posk(c);
    float v = 0.f;
    float4 cur = *reinterpret_cast<const float4*>(xr);
    for (int n = 0; n < 400; n += 4) {
        float4 nxt = cur;
        if (n + 4 < 400) nxt = *reinterpret_cast<const float4*>(xr + n + 4);
        float xa[4] = {cur.x, cur.y, cur.z, cur.w};
        #pragma unroll
        for (int j = 0; j < 4; ++j) {
            v += (xa[j] - v) * 0.5f;
            bool sk = (v >= 1.0f);
            sp[((long)(n + j) * 64 + b) * 1024] = sk ? (unsigned short)0x3F80 : (unsigned short)0;
            if (sk) v = 0.f;
        }
        cur = nxt;
    }
}

// ---------------- LIF2: y[(n*64+b)][o] f32 -> s2[(n*64+b)][posk(o)] (o<448) ----------------
__global__ __launch_bounds__(64) void lif2(const float* __restrict__ y, unsigned short* __restrict__ s2)
{
    int o = blockIdx.x * 64 + threadIdx.x;   // 0..511
    int b = blockIdx.y;
    const float* yp = y + (long)b * 512 + o;
    unsigned short* s2p = s2 + (long)b * 448 + ((o < 448) ? posk(o) : 0);
    float v = 0.f;
    float buf[8];
    #pragma unroll
    for (int j = 0; j < 8; ++j) buf[j] = yp[(long)j * 32768];
    for (int n0 = 0; n0 < 400; n0 += 8) {
        #pragma unroll
        for (int j = 0; j < 8; ++j) {
            float cur = buf[j];
            int np = n0 + j + 8;
            if (np < 400) buf[j] = yp[(long)np * 32768];
            v += (cur - v) * 0.5f;
            bool sk = (v >= 1.0f);
            if (o < 448) s2p[(long)(n0 + j) * 28672] = sk ? (unsigned short)0x3F80 : (unsigned short)0;
            if (sk) v = 0.f;
        }
    }
}

// ---------------- MFMA GEMM: D[m][n] = sum_k A[m][k]*B[n][k] (both NT, bf16, posk-permuted K) ----
// 128x128 tile, BK=64, 4 waves (2x2), 4x4 16x16x32 frags per wave.
// EPI 0: h1 = relu(acc + p0[col]) bf16 @ [row][448], posk cols, col<448
// EPI 1: x1bf = acc + p0[row] + xT            (col=(b,c): row<400)
// EPI 2: y = acc*p0[col] + p1[col]  f32 @ [row][512]
// EPI 3: x1bf[(b*400+n)][posk(col)] += acc*p0[col]+p1[col]   (row=(n*64+b))
// EPI 4: xc[bz][row][col] = acc + p0[col]  f32, row<400
template<int EPI>
__global__ __launch_bounds__(256) void mfma_gemm(
    const unsigned short* __restrict__ A, int ldA, long sAb,
    const unsigned short* __restrict__ B, int ldB,
    int KT, int wrapK,
    void* __restrict__ Cv,
    const float* __restrict__ p0, const float* __restrict__ p1)
{
    __shared__ char AsB[16384];
    __shared__ char BsB[16384];
    const int tid = threadIdx.x;
    const int lane = tid & 63, wid = tid >> 6;
    const int wm = wid >> 1, wn = wid & 1;
    const int m0 = blockIdx.y << 7, n0 = blockIdx.x << 7;
    const int bz = blockIdx.z;
    const unsigned short* Ab = A + (long)bz * sAb;

    const int srow = lane >> 3;                 // row within 8-row instr group
    const int koff = (lane & 7) << 4;           // 16B chunk within 128B row
    const int ssw  = (srow & 7) << 4;           // bank swizzle (row&7)<<4

    f32x4 acc[4][4];
    #pragma unroll
    for (int i = 0; i < 4; ++i)
        #pragma unroll
        for (int j = 0; j < 4; ++j)
            acc[i][j] = (f32x4){0.f, 0.f, 0.f, 0.f};

    for (int kt = 0; kt < KT; ++kt) {
        int k0 = kt << 6;
        int k0a = (wrapK && k0 >= wrapK) ? (k0 - wrapK) : k0;
        __syncthreads();
        #pragma unroll
        for (int q = 0; q < 4; ++q) {
            int i = (wid << 2) + q;
            int row = (i << 3) + srow;
            const char* gA = (const char*)(Ab + (long)(m0 + row) * ldA + k0a) + (koff ^ ssw);
            async16(gA, AsB + (i << 10));
            const char* gB = (const char*)(B + (long)(n0 + row) * ldB + k0) + (koff ^ ssw);
            async16(gB, BsB + (i << 10));
        }
        __syncthreads();   // emits vmcnt(0) drain before barrier
        const int r16 = lane & 15;
        const int swl = (r16 & 7) << 4;
        #pragma unroll
        for (int kk = 0; kk < 2; ++kk) {
            int kb = (kk << 6) + ((lane >> 4) << 4);
            s8v af[4], bv[4];
            #pragma unroll
            for (int f = 0; f < 4; ++f) {
                int rowA = (wm << 6) + (f << 4) + r16;
                af[f] = *reinterpret_cast<const s8v*>(AsB + (rowA << 7) + (kb ^ swl));
                int rowB = (wn << 6) + (f << 4) + r16;
                bv[f] = *reinterpret_cast<const s8v*>(BsB + (rowB << 7) + (kb ^ swl));
            }
            #pragma unroll
            for (int fi = 0; fi < 4; ++fi)
                #pragma unroll
                for (int fj = 0; fj < 4; ++fj)
                    acc[fi][fj] = __builtin_amdgcn_mfma_f32_16x16x32_bf16(af[fi], bv[fj], acc[fi][fj], 0, 0, 0);
        }
    }

    const int r16 = lane & 15, g4 = (lane >> 4) << 2;
    unsigned short* hC = (unsigned short*)Cv;
    float* fC = (float*)Cv;
    #pragma unroll
    for (int fi = 0; fi < 4; ++fi) {
        #pragma unroll
        for (int fj = 0; fj < 4; ++fj) {
            int col = n0 + (wn << 6) + (fj << 4) + r16;
            int row0 = m0 + (wm << 6) + (fi << 4) + g4;
            f32x4 a = acc[fi][fj];
            if (EPI == 0) {
                if (col < 448) {
                    float bias = p0[col];
                    int pc = posk(col);
                    #pragma unroll
                    for (int r = 0; r < 4; ++r)
                        hC[(long)(row0 + r) * 448 + pc] = f2bf(fmaxf(a[r] + bias, 0.f));
                }
            } else if (EPI == 1) {
                int bb = col >> 10, cc = col & 1023;
                long rb = (long)bb * 409600;
                int pc = posk(cc);
                #pragma unroll
                for (int r = 0; r < 4; ++r) {
                    int row = row0 + r;
                    if (row < 400) {
                        float t = a[r] + p0[row] + p1[rb + (long)row * 1024 + cc];
                        hC[rb + (long)row * 1024 + pc] = f2bf(t);
                    }
                }
            } else if (EPI == 2) {
                float sc = p0[col], sh = p1[col];
                #pragma unroll
                for (int r = 0; r < 4; ++r)
                    fC[(long)(row0 + r) * 512 + col] = a[r] * sc + sh;
            } else if (EPI == 3) {
                float sc = p0[col], sh = p1[col];
                int pc = posk(col);
                #pragma unroll
                for (int r = 0; r < 4; ++r) {
                    int row = row0 + r;
                    int nn = row >> 6, bbb = row & 63;
                    long ad = ((long)bbb * 400 + nn) * 1024 + pc;
                    hC[ad] = f2bf(bf2f(hC[ad]) + a[r] * sc + sh);
                }
            } else {
                float bias = p0[col];
                #pragma unroll
                for (int r = 0; r < 4; ++r) {
                    int row = row0 + r;
                    if (row < 400)
                        fC[(long)bz * 204800 + (long)row * 512 + col] = a[r] + bias;
                }
            }
        }
    }
}

// ---------------- rp GEMM (K=400, R=4) + L2 normalize; xc[b][n][o] layout ----------------
__global__ __launch_bounds__(512) void rp_norm(const float* __restrict__ xc,
        const float* __restrict__ rpw, const float* __restrict__ rpb,
        float* __restrict__ out)
{
    __shared__ float wr[1600];
    __shared__ float red[8];
    int b = blockIdx.x, o = threadIdx.x;
    for (int i = o; i < 1600; i += 512) wr[i] = rpw[i];
    __syncthreads();
    const float* xb = xc + (long)b * 204800 + o;
    float a0 = rpb[0], a1 = rpb[1], a2 = rpb[2], a3 = rpb[3];
    for (int n = 0; n < 400; ++n) {
        float xv = xb[(long)n * 512];
        a0 = fmaf(xv, wr[n], a0);
        a1 = fmaf(xv, wr[400 + n], a1);
        a2 = fmaf(xv, wr[800 + n], a2);
        a3 = fmaf(xv, wr[1200 + n], a3);
    }
    float sq = a0*a0 + a1*a1 + a2*a2 + a3*a3;
    #pragma unroll
    for (int off2 = 32; off2; off2 >>= 1) sq += __shfl_down(sq, off2);
    if ((o & 63) == 0) red[o >> 6] = sq;
    __syncthreads();
    if (o == 0) {
        float t = 0.f;
        #pragma unroll
        for (int i = 0; i < 8; ++i) t += red[i];
        red[0] = fmaxf(sqrtf(t), 1e-12f);
    }
    __syncthreads();
    float inv = 1.f / red[0];
    float4 ov = make_float4(a0*inv, a1*inv, a2*inv, a3*inv);
    *reinterpret_cast<float4*>(out + (long)b * 2048 + o * 4) = ov;
}

extern "C" void kernel_launch(void* const* d_in, const int* in_sizes, int n_in,
                              void* d_out, int out_size, void* d_ws, size_t ws_size,
                              hipStream_t stream) {
    const float* x    = (const float*)d_in[0];
    const float* ln_g = (const float*)d_in[1];
    const float* ln_b = (const float*)d_in[2];
    const float* w1   = (const float*)d_in[3];
    const float* b1   = (const float*)d_in[4];
    const float* w2   = (const float*)d_in[5];
    const float* b2   = (const float*)d_in[6];
    const float* c1w  = (const float*)d_in[7];
    const float* c1b  = (const float*)d_in[8];
    const float* bn1g = (const float*)d_in[9];
    const float* bn1b = (const float*)d_in[10];
    const float* bn1m = (const float*)d_in[11];
    const float* bn1v = (const float*)d_in[12];
    const float* c2w  = (const float*)d_in[13];
    const float* c2b  = (const float*)d_in[14];
    const float* bn2g = (const float*)d_in[15];
    const float* bn2b = (const float*)d_in[16];
    const float* bn2m = (const float*)d_in[17];
    const float* bn2v = (const float*)d_in[18];
    const float* cpw  = (const float*)d_in[19];
    const float* cpb  = (const float*)d_in[20];
    const float* rpw  = (const float*)d_in[21];
    const float* rpb  = (const float*)d_in[22];

    char* ws = (char*)d_ws;
    size_t off = 0;
    auto alloc = [&](size_t n){ size_t o = off; off += (n + 255) & ~(size_t)255; return o; };

    // Region A: xln (GEMM1 A) -> later x1bf (GEMM2 out, conv2 RMW, cp A)
    unsigned short* regA = (unsigned short*)(ws + alloc(58720256));
    // Region B: h1 -> later s (LIF1 spikes)
    unsigned short* regB = (unsigned short*)(ws + alloc(58720256));
    // Region C: xT -> later y + s2 -> later xc
    char* regC = ws + alloc(104857600);

    unsigned short* xln  = regA;
    unsigned short* x1bf = regA;                   // 25728*1024*2 = 52,690,944 <= 58,720,256
    unsigned short* h1   = regB;
    unsigned short* s    = regB;                   // 25600*1024*2
    float* xT = (float*)regC;                      // 64*400*1024*4
    float* y  = (float*)regC;                      // 25600*512*4 = 52,428,800
    unsigned short* s2 = (unsigned short*)(regC + 52428800); // 25600*448*2 = 22,937,600
    float* xc = (float*)regC;                      // 64*400*512*4 (after conv2)

    unsigned short* w1p  = (unsigned short*)(ws + alloc(458752));   // [512][448]
    unsigned short* w2p  = (unsigned short*)(ws + alloc(458752));   // [512][448]
    unsigned short* w1c  = (unsigned short*)(ws + alloc(2097152));  // [512][2048] hi|lo
    unsigned short* w2c  = (unsigned short*)(ws + alloc(1835008));  // [1024][896] hi|lo
    unsigned short* cpwp = (unsigned short*)(ws + alloc(1048576));  // [512][1024]
    float* b1p = (float*)(ws + alloc(2048));
    float* b2p = (float*)(ws + alloc(2048));
    float* sc1 = (float*)(ws + alloc(2048));
    float* sh1 = (float*)(ws + alloc(2048));
    float* sc2 = (float*)(ws + alloc(4096));
    float* sh2 = (float*)(ws + alloc(4096));

    // weight / param prep
    prep_w<<<dim3(2, 512), 256, 0, stream>>>(w1, 400, 400, w1p, 448, 0);
    prep_w<<<dim3(2, 512), 256, 0, stream>>>(w2, 400, 400, w2p, 448, 0);
    prep_w<<<dim3(8, 512), 256, 0, stream>>>(c1w, 400, 1024, w1c, 2048, 1024);
    prep_w<<<dim3(4, 1024), 256, 0, stream>>>(c2w, 1024, 400, w2c, 896, 448);
    prep_w<<<dim3(4, 512), 256, 0, stream>>>(cpw, 512, 1024, cpwp, 1024, 0);
    prep_params<<<1, 1024, 0, stream>>>(b1, b2, c1b, bn1g, bn1b, bn1m, bn1v,
                                        c2b, bn2g, bn2b, bn2m, bn2v,
                                        b1p, b2p, sc1, sh1, sc2, sh2);

    // 1) LN(x) -> xln bf16 [65536][448]
    ln_fused<<<16384, 256, 0, stream>>>(x, ln_g, ln_b, xln);

    // 2) h1 = relu(xln @ w1p^T + b1)  [65536][448] bf16
    mfma_gemm<0><<<dim3(4, 512, 1), 256, 0, stream>>>(xln, 448, 0, w1p, 448, 7, 0, h1, b1p, nullptr);

    // 3) xT = transpose(x) -> [b][n][c] f32
    transpose_x<<<dim3(16, 7, 64), 256, 0, stream>>>(x, xT);

    // 4) x1bf[b][n][c] = (h1 @ w2^T)^T + b2 + xT   (swapped: M'=n, N'=(b,c))
    mfma_gemm<1><<<dim3(512, 4, 1), 256, 0, stream>>>(w2p, 448, 0, h1, 448, 7, 0, x1bf, b2p, xT);

    // 5) LIF1: x -> s[(n*64+b)][c] spikes
    lif1<<<dim3(4, 64), 256, 0, stream>>>(x, s);

    // 6) conv1+bn1 (split hi/lo, K=2048 wrap 1024): y[(nb)][o] = bn1(s @ c1w^T)
    mfma_gemm<2><<<dim3(4, 200, 1), 256, 0, stream>>>(s, 1024, 0, w1c, 2048, 32, 1024, y, sc1, sh1);

    // 7) LIF2: y -> s2[(nb)][o]
    lif2<<<dim3(8, 64), 64, 0, stream>>>(y, s2);

    // 8) conv2+bn2 (split, K=896 wrap 448): x1bf += bn2(s2 @ c2w^T)  (RMW)
    mfma_gemm<3><<<dim3(8, 200, 1), 256, 0, stream>>>(s2, 448, 0, w2c, 896, 14, 448, x1bf, sc2, sh2);

    // 9) cp: xc[b][n][o] = x1bf[b] @ cpw^T + cpb   (batched, swapped)
    mfma_gemm<4><<<dim3(4, 4, 64), 256, 0, stream>>>(x1bf, 1024, 409600, cpwp, 1024, 16, 0, xc, cpb, nullptr);

    // 10) rp + L2 normalize
    rp_norm<<<64, 512, 0, stream>>>(xc, rpw, rpb, (float*)d_out);
}

// Round 3
// 714.289 us; speedup vs baseline: 2.7463x; 1.0061x over previous
//
#include <hip/hip_runtime.h>
#include <hip/hip_bf16.h>

typedef __attribute__((ext_vector_type(8))) short s8v;
typedef __attribute__((ext_vector_type(4))) float f32x4;
using bf16 = __hip_bfloat16;

#define LN_EPS 1e-5f

__device__ __forceinline__ float bf2f(unsigned short b){ return __uint_as_float(((unsigned)b)<<16); }
__device__ __forceinline__ unsigned short f2bf(float f){ __hip_bfloat16 h = __float2bfloat16(f); return *reinterpret_cast<unsigned short*>(&h); }

// MFMA k-half permutation: stored position of true k within each 32-k block.
__device__ __forceinline__ int posk(int k){
    int q = (k >> 2) & 7;
    int s = (q < 4) ? (2*q) : (2*q - 7);
    return (k & ~31) | (s << 2) | (k & 3);
}

__device__ __forceinline__ void async16(const void* g, void* l){
    __builtin_amdgcn_global_load_lds(
        (const __attribute__((address_space(1))) unsigned int*)g,
        (__attribute__((address_space(3))) unsigned int*)l, 16, 0, 0);
}

// ---------------- fused LayerNorm -> padded+permuted bf16 A-matrix ----------------
__global__ __launch_bounds__(256) void ln_fused(const float* __restrict__ x,
        const float* __restrict__ g, const float* __restrict__ b,
        unsigned short* __restrict__ xln)
{
    int lane = threadIdx.x & 63, wv = threadIdx.x >> 6;
    long row = (long)blockIdx.x * 4 + wv;
    const float* xr = x + row * 400;
    float v[7];
    float s = 0.f, ss = 0.f;
    #pragma unroll
    for (int i = 0; i < 7; ++i) {
        int n = lane + i * 64;
        float t = (n < 400) ? xr[n] : 0.f;
        v[i] = t; s += t; ss += t * t;
    }
    #pragma unroll
    for (int o = 32; o; o >>= 1) { s += __shfl_down(s, o); ss += __shfl_down(ss, o); }
    s = __shfl(s, 0); ss = __shfl(ss, 0);
    float mu = s * 0.0025f;
    float rstd = rsqrtf(ss * 0.0025f - mu * mu + LN_EPS);
    unsigned short* orow = xln + row * 448;
    #pragma unroll
    for (int i = 0; i < 7; ++i) {
        int n = lane + i * 64;
        float t = (n < 400) ? ((v[i] - mu) * rstd * g[n] + b[n]) : 0.f;
        orow[posk(n)] = f2bf(t);
    }
}

// ---------------- x[b][c][n] -> xT[b][n][c] f32 ----------------
__global__ __launch_bounds__(256) void transpose_x(const float* __restrict__ x, float* __restrict__ xT)
{
    __shared__ float tile[64][65];
    int b = blockIdx.z, n0 = blockIdx.y * 64, c0 = blockIdx.x * 64;
    int lane = threadIdx.x & 63, wv = threadIdx.x >> 6;
    int n = n0 + lane;
    #pragma unroll
    for (int q = 0; q < 16; ++q) {
        int cc = wv * 16 + q;
        tile[cc][lane] = (n < 400) ? x[((long)b * 1024 + c0 + cc) * 400 + n] : 0.f;
    }
    __syncthreads();
    #pragma unroll
    for (int q = 0; q < 16; ++q) {
        int nn = wv * 16 + q;
        if (n0 + nn < 400)
            xT[((long)b * 400 + n0 + nn) * 1024 + c0 + lane] = tile[lane][nn];
    }
}

// ---------------- weight prep: pad + posk-permute + optional hi/lo split along K ----------------
__global__ void prep_w(const float* __restrict__ src, int R0, int K0,
                       unsigned short* __restrict__ dst, int K2, int khalf)
{
    int k = blockIdx.x * 256 + threadIdx.x;
    if (k >= K2) return;
    int r = blockIdx.y;
    int ks = k, half = 0;
    if (khalf && k >= khalf) { ks = k - khalf; half = 1; }
    float v = 0.f;
    if (r < R0 && ks < K0) v = src[(long)r * K0 + ks];
    unsigned short out;
    if (!khalf) out = f2bf(v);
    else {
        float hi = bf2f(f2bf(v));
        out = half ? f2bf(v - hi) : f2bf(hi);
    }
    dst[(long)r * K2 + posk(k)] = out;
}

// ---------------- param prep ----------------
__global__ void prep_params(
    const float* __restrict__ b1, const float* __restrict__ b2,
    const float* __restrict__ c1b, const float* __restrict__ g1, const float* __restrict__ bb1,
    const float* __restrict__ m1, const float* __restrict__ v1,
    const float* __restrict__ c2b, const float* __restrict__ g2, const float* __restrict__ bb2,
    const float* __restrict__ m2, const float* __restrict__ v2,
    float* __restrict__ b1p, float* __restrict__ b2p,
    float* __restrict__ sc1, float* __restrict__ sh1,
    float* __restrict__ sc2, float* __restrict__ sh2)
{
    int t = threadIdx.x;
    if (t < 512) {
        b1p[t] = (t < 400) ? b1[t] : 0.f;
        b2p[t] = (t < 400) ? b2[t] : 0.f;
        float sc = 0.f, sh = 0.f;
        if (t < 400) { sc = g1[t] / sqrtf(v1[t] + LN_EPS); sh = (c1b[t] - m1[t]) * sc + bb1[t]; }
        sc1[t] = sc; sh1[t] = sh;
    }
    float sc = g2[t] / sqrtf(v2[t] + LN_EPS);
    sc2[t] = sc;
    sh2[t] = (c2b[t] - m2[t]) * sc + bb2[t];
}

// ---------------- LIF1: xT[b][n][c] (coalesced scan) -> s[(n*64+b)][posk(c)] ----------------
__global__ __launch_bounds__(256) void lif1(const float* __restrict__ xT, unsigned short* __restrict__ s)
{
    int c = blockIdx.x * 256 + threadIdx.x;
    int b = blockIdx.y;
    const float* xp = xT + (long)b * 409600 + c;          // stride 1024 per n
    unsigned short* sp = s + (long)b * 1024 + posk(c);    // stride 65536 per n
    float v = 0.f;
    float buf[8];
    #pragma unroll
    for (int j = 0; j < 8; ++j) buf[j] = xp[(long)j * 1024];
    for (int n0 = 0; n0 < 400; n0 += 8) {
        #pragma unroll
        for (int j = 0; j < 8; ++j) {
            float cur = buf[j];
            int np = n0 + j + 8;
            if (np < 400) buf[j] = xp[(long)np * 1024];
            v += (cur - v) * 0.5f;
            bool sk = (v >= 1.0f);
            sp[(long)(n0 + j) * 65536] = sk ? (unsigned short)0x3F80 : (unsigned short)0;
            if (sk) v = 0.f;
        }
    }
}

// ---------------- LIF2: LDS-staged scan over y[(n*64+b)][o] -> s2[(n*64+b)][posk(o)] ----------
// grid (4,64), 128 threads. Chunk = 40 timesteps x 128 outputs staged via global_load_lds.
__global__ __launch_bounds__(128) void lif2(const float* __restrict__ y, unsigned short* __restrict__ s2)
{
    __shared__ float buf[40][128];
    const int tid = threadIdx.x;
    const int lane = tid & 63, w = tid >> 6;
    const int o0 = blockIdx.x * 128, b = blockIdx.y;
    const int o = o0 + tid;
    const int pco = (o < 448) ? posk(o) : 0;
    const int rsub = lane >> 5;            // row within 1KB issue
    const int koff = (lane & 31) << 2;     // f32 index within 512B row
    float v = 0.f;
    for (int n0 = 0; n0 < 400; n0 += 40) {
        #pragma unroll
        for (int g = 0; g < 10; ++g) {
            int r = w * 20 + g * 2;
            const float* src = y + ((long)(n0 + r + rsub) * 64 + b) * 512 + o0 + koff;
            async16(src, &buf[r][0]);
        }
        __syncthreads();
        #pragma unroll 8
        for (int r = 0; r < 40; ++r) {
            float cur = buf[r][tid];
            v += (cur - v) * 0.5f;
            bool sk = (v >= 1.0f);
            if (o < 448)
                s2[((long)(n0 + r) * 64 + b) * 448 + pco] = sk ? (unsigned short)0x3F80 : (unsigned short)0;
            if (sk) v = 0.f;
        }
        __syncthreads();
    }
}

// ---------------- MFMA GEMM (unchanged from round 1) ----------------
template<int EPI>
__global__ __launch_bounds__(256) void mfma_gemm(
    const unsigned short* __restrict__ A, int ldA, long sAb,
    const unsigned short* __restrict__ B, int ldB,
    int KT, int wrapK,
    void* __restrict__ Cv,
    const float* __restrict__ p0, const float* __restrict__ p1)
{
    __shared__ char AsB[16384];
    __shared__ char BsB[16384];
    const int tid = threadIdx.x;
    const int lane = tid & 63, wid = tid >> 6;
    const int wm = wid >> 1, wn = wid & 1;
    const int m0 = blockIdx.y << 7, n0 = blockIdx.x << 7;
    const int bz = blockIdx.z;
    const unsigned short* Ab = A + (long)bz * sAb;

    const int srow = lane >> 3;
    const int koff = (lane & 7) << 4;
    const int ssw  = (srow & 7) << 4;

    f32x4 acc[4][4];
    #pragma unroll
    for (int i = 0; i < 4; ++i)
        #pragma unroll
        for (int j = 0; j < 4; ++j)
            acc[i][j] = (f32x4){0.f, 0.f, 0.f, 0.f};

    for (int kt = 0; kt < KT; ++kt) {
        int k0 = kt << 6;
        int k0a = (wrapK && k0 >= wrapK) ? (k0 - wrapK) : k0;
        __syncthreads();
        #pragma unroll
        for (int q = 0; q < 4; ++q) {
            int i = (wid << 2) + q;
            int row = (i << 3) + srow;
            const char* gA = (const char*)(Ab + (long)(m0 + row) * ldA + k0a) + (koff ^ ssw);
            async16(gA, AsB + (i << 10));
            const char* gB = (const char*)(B + (long)(n0 + row) * ldB + k0) + (koff ^ ssw);
            async16(gB, BsB + (i << 10));
        }
        __syncthreads();
        const int r16 = lane & 15;
        const int swl = (r16 & 7) << 4;
        #pragma unroll
        for (int kk = 0; kk < 2; ++kk) {
            int kb = (kk << 6) + ((lane >> 4) << 4);
            s8v af[4], bv[4];
            #pragma unroll
            for (int f = 0; f < 4; ++f) {
                int rowA = (wm << 6) + (f << 4) + r16;
                af[f] = *reinterpret_cast<const s8v*>(AsB + (rowA << 7) + (kb ^ swl));
                int rowB = (wn << 6) + (f << 4) + r16;
                bv[f] = *reinterpret_cast<const s8v*>(BsB + (rowB << 7) + (kb ^ swl));
            }
            #pragma unroll
            for (int fi = 0; fi < 4; ++fi)
                #pragma unroll
                for (int fj = 0; fj < 4; ++fj)
                    acc[fi][fj] = __builtin_amdgcn_mfma_f32_16x16x32_bf16(af[fi], bv[fj], acc[fi][fj], 0, 0, 0);
        }
    }

    const int r16 = lane & 15, g4 = (lane >> 4) << 2;
    unsigned short* hC = (unsigned short*)Cv;
    float* fC = (float*)Cv;
    #pragma unroll
    for (int fi = 0; fi < 4; ++fi) {
        #pragma unroll
        for (int fj = 0; fj < 4; ++fj) {
            int col = n0 + (wn << 6) + (fj << 4) + r16;
            int row0 = m0 + (wm << 6) + (fi << 4) + g4;
            f32x4 a = acc[fi][fj];
            if (EPI == 0) {
                if (col < 448) {
                    float bias = p0[col];
                    int pc = posk(col);
                    #pragma unroll
                    for (int r = 0; r < 4; ++r)
                        hC[(long)(row0 + r) * 448 + pc] = f2bf(fmaxf(a[r] + bias, 0.f));
                }
            } else if (EPI == 1) {
                int bb = col >> 10, cc = col & 1023;
                long rb = (long)bb * 409600;
                int pc = posk(cc);
                #pragma unroll
                for (int r = 0; r < 4; ++r) {
                    int row = row0 + r;
                    if (row < 400) {
                        float t = a[r] + p0[row] + p1[rb + (long)row * 1024 + cc];
                        hC[rb + (long)row * 1024 + pc] = f2bf(t);
                    }
                }
            } else if (EPI == 2) {
                float sc = p0[col], sh = p1[col];
                #pragma unroll
                for (int r = 0; r < 4; ++r)
                    fC[(long)(row0 + r) * 512 + col] = a[r] * sc + sh;
            } else if (EPI == 3) {
                float sc = p0[col], sh = p1[col];
                int pc = posk(col);
                #pragma unroll
                for (int r = 0; r < 4; ++r) {
                    int row = row0 + r;
                    int nn = row >> 6, bbb = row & 63;
                    long ad = ((long)bbb * 400 + nn) * 1024 + pc;
                    hC[ad] = f2bf(bf2f(hC[ad]) + a[r] * sc + sh);
                }
            } else {
                float bias = p0[col];
                #pragma unroll
                for (int r = 0; r < 4; ++r) {
                    int row = row0 + r;
                    if (row < 400)
                        fC[(long)bz * 204800 + (long)row * 512 + col] = a[r] + bias;
                }
            }
        }
    }
}

// ---------------- rp GEMM + L2 normalize ----------------
__global__ __launch_bounds__(512) void rp_norm(const float* __restrict__ xc,
        const float* __restrict__ rpw, const float* __restrict__ rpb,
        float* __restrict__ out)
{
    __shared__ float wr[1600];
    __shared__ float red[8];
    int b = blockIdx.x, o = threadIdx.x;
    for (int i = o; i < 1600; i += 512) wr[i] = rpw[i];
    __syncthreads();
    const float* xb = xc + (long)b * 204800 + o;
    float a0 = rpb[0], a1 = rpb[1], a2 = rpb[2], a3 = rpb[3];
    #pragma unroll 4
    for (int n = 0; n < 400; ++n) {
        float xv = xb[(long)n * 512];
        a0 = fmaf(xv, wr[n], a0);
        a1 = fmaf(xv, wr[400 + n], a1);
        a2 = fmaf(xv, wr[800 + n], a2);
        a3 = fmaf(xv, wr[1200 + n], a3);
    }
    float sq = a0*a0 + a1*a1 + a2*a2 + a3*a3;
    #pragma unroll
    for (int off2 = 32; off2; off2 >>= 1) sq += __shfl_down(sq, off2);
    if ((o & 63) == 0) red[o >> 6] = sq;
    __syncthreads();
    if (o == 0) {
        float t = 0.f;
        #pragma unroll
        for (int i = 0; i < 8; ++i) t += red[i];
        red[0] = fmaxf(sqrtf(t), 1e-12f);
    }
    __syncthreads();
    float inv = 1.f / red[0];
    float4 ov = make_float4(a0*inv, a1*inv, a2*inv, a3*inv);
    *reinterpret_cast<float4*>(out + (long)b * 2048 + o * 4) = ov;
}

extern "C" void kernel_launch(void* const* d_in, const int* in_sizes, int n_in,
                              void* d_out, int out_size, void* d_ws, size_t ws_size,
                              hipStream_t stream) {
    const float* x    = (const float*)d_in[0];
    const float* ln_g = (const float*)d_in[1];
    const float* ln_b = (const float*)d_in[2];
    const float* w1   = (const float*)d_in[3];
    const float* b1   = (const float*)d_in[4];
    const float* w2   = (const float*)d_in[5];
    const float* b2   = (const float*)d_in[6];
    const float* c1w  = (const float*)d_in[7];
    const float* c1b  = (const float*)d_in[8];
    const float* bn1g = (const float*)d_in[9];
    const float* bn1b = (const float*)d_in[10];
    const float* bn1m = (const float*)d_in[11];
    const float* bn1v = (const float*)d_in[12];
    const float* c2w  = (const float*)d_in[13];
    const float* c2b  = (const float*)d_in[14];
    const float* bn2g = (const float*)d_in[15];
    const float* bn2b = (const float*)d_in[16];
    const float* bn2m = (const float*)d_in[17];
    const float* bn2v = (const float*)d_in[18];
    const float* cpw  = (const float*)d_in[19];
    const float* cpb  = (const float*)d_in[20];
    const float* rpw  = (const float*)d_in[21];
    const float* rpb  = (const float*)d_in[22];

    char* ws = (char*)d_ws;
    size_t off = 0;
    auto alloc = [&](size_t n){ size_t o = off; off += (n + 255) & ~(size_t)255; return o; };

    unsigned short* regA = (unsigned short*)(ws + alloc(58720256));
    unsigned short* regB = (unsigned short*)(ws + alloc(58720256));
    char* regC = ws + alloc(104857600);

    unsigned short* xln  = regA;
    unsigned short* x1bf = regA;
    unsigned short* h1   = regB;
    unsigned short* s    = regB;
    float* xT = (float*)regC;
    float* y  = (float*)regC;
    unsigned short* s2 = (unsigned short*)(regC + 52428800);
    float* xc = (float*)regC;

    unsigned short* w1p  = (unsigned short*)(ws + alloc(458752));
    unsigned short* w2p  = (unsigned short*)(ws + alloc(458752));
    unsigned short* w1c  = (unsigned short*)(ws + alloc(2097152));
    unsigned short* w2c  = (unsigned short*)(ws + alloc(1835008));
    unsigned short* cpwp = (unsigned short*)(ws + alloc(1048576));
    float* b1p = (float*)(ws + alloc(2048));
    float* b2p = (float*)(ws + alloc(2048));
    float* sc1 = (float*)(ws + alloc(2048));
    float* sh1 = (float*)(ws + alloc(2048));
    float* sc2 = (float*)(ws + alloc(4096));
    float* sh2 = (float*)(ws + alloc(4096));

    prep_w<<<dim3(2, 512), 256, 0, stream>>>(w1, 400, 400, w1p, 448, 0);
    prep_w<<<dim3(2, 512), 256, 0, stream>>>(w2, 400, 400, w2p, 448, 0);
    prep_w<<<dim3(8, 512), 256, 0, stream>>>(c1w, 400, 1024, w1c, 2048, 1024);
    prep_w<<<dim3(4, 1024), 256, 0, stream>>>(c2w, 1024, 400, w2c, 896, 448);
    prep_w<<<dim3(4, 512), 256, 0, stream>>>(cpw, 512, 1024, cpwp, 1024, 0);
    prep_params<<<1, 1024, 0, stream>>>(b1, b2, c1b, bn1g, bn1b, bn1m, bn1v,
                                        c2b, bn2g, bn2b, bn2m, bn2v,
                                        b1p, b2p, sc1, sh1, sc2, sh2);

    // 1) LN(x) -> xln
    ln_fused<<<16384, 256, 0, stream>>>(x, ln_g, ln_b, xln);

    // 2) h1 = relu(xln @ w1p^T + b1)
    mfma_gemm<0><<<dim3(4, 512, 1), 256, 0, stream>>>(xln, 448, 0, w1p, 448, 7, 0, h1, b1p, nullptr);

    // 3) xT = transpose(x)
    transpose_x<<<dim3(16, 7, 64), 256, 0, stream>>>(x, xT);

    // 4) x1bf[b][n][c] = (h1 @ w2^T)^T + b2 + xT
    mfma_gemm<1><<<dim3(512, 4, 1), 256, 0, stream>>>(w2p, 448, 0, h1, 448, 7, 0, x1bf, b2p, xT);

    // 5) LIF1 (reads xT, coalesced): -> s
    lif1<<<dim3(4, 64), 256, 0, stream>>>(xT, s);

    // 6) conv1+bn1: y = bn1(s @ c1w^T)   [regC: xT dead after steps 4&5]
    mfma_gemm<2><<<dim3(4, 200, 1), 256, 0, stream>>>(s, 1024, 0, w1c, 2048, 32, 1024, y, sc1, sh1);

    // 7) LIF2 (LDS-staged): y -> s2
    lif2<<<dim3(4, 64), 128, 0, stream>>>(y, s2);

    // 8) conv2+bn2 (RMW into x1bf)
    mfma_gemm<3><<<dim3(8, 200, 1), 256, 0, stream>>>(s2, 448, 0, w2c, 896, 14, 448, x1bf, sc2, sh2);

    // 9) cp: xc[b][n][o] = x1bf[b] @ cpw^T + cpb
    mfma_gemm<4><<<dim3(4, 4, 64), 256, 0, stream>>>(x1bf, 1024, 409600, cpwp, 1024, 16, 0, xc, cpb, nullptr);

    // 10) rp + L2 normalize
    rp_norm<<<64, 512, 0, stream>>>(xc, rpw, rpb, (float*)d_out);
}

// Round 4
// 611.601 us; speedup vs baseline: 3.2074x; 1.1679x over previous
//
#include <hip/hip_runtime.h>
#include <hip/hip_bf16.h>

typedef __attribute__((ext_vector_type(8))) short s8v;
typedef __attribute__((ext_vector_type(4))) float f32x4;
using bf16 = __hip_bfloat16;

#define LN_EPS 1e-5f

__device__ __forceinline__ float bf2f(unsigned short b){ return __uint_as_float(((unsigned)b)<<16); }
__device__ __forceinline__ unsigned short f2bf(float f){ __hip_bfloat16 h = __float2bfloat16(f); return *reinterpret_cast<unsigned short*>(&h); }

// MFMA k-half permutation: stored position of true k within each 32-k block.
__device__ __forceinline__ int posk(int k){
    int q = (k >> 2) & 7;
    int s = (q < 4) ? (2*q) : (2*q - 7);
    return (k & ~31) | (s << 2) | (k & 3);
}

__device__ __forceinline__ void async16(const void* g, void* l){
    __builtin_amdgcn_global_load_lds(
        (const __attribute__((address_space(1))) unsigned int*)g,
        (__attribute__((address_space(3))) unsigned int*)l, 16, 0, 0);
}

// ---------------- fused LayerNorm -> padded+permuted bf16 A-matrix ----------------
__global__ __launch_bounds__(256) void ln_fused(const float* __restrict__ x,
        const float* __restrict__ g, const float* __restrict__ b,
        unsigned short* __restrict__ xln)
{
    int lane = threadIdx.x & 63, wv = threadIdx.x >> 6;
    long row = (long)blockIdx.x * 4 + wv;
    const float* xr = x + row * 400;
    float v[7];
    float s = 0.f, ss = 0.f;
    #pragma unroll
    for (int i = 0; i < 7; ++i) {
        int n = lane + i * 64;
        float t = (n < 400) ? xr[n] : 0.f;
        v[i] = t; s += t; ss += t * t;
    }
    #pragma unroll
    for (int o = 32; o; o >>= 1) { s += __shfl_down(s, o); ss += __shfl_down(ss, o); }
    s = __shfl(s, 0); ss = __shfl(ss, 0);
    float mu = s * 0.0025f;
    float rstd = rsqrtf(ss * 0.0025f - mu * mu + LN_EPS);
    unsigned short* orow = xln + row * 448;
    #pragma unroll
    for (int i = 0; i < 7; ++i) {
        int n = lane + i * 64;
        float t = (n < 400) ? ((v[i] - mu) * rstd * g[n] + b[n]) : 0.f;
        orow[posk(n)] = f2bf(t);
    }
}

// ---------------- x[b][c][n] -> xT[b][n][c] f32 ----------------
__global__ __launch_bounds__(256) void transpose_x(const float* __restrict__ x, float* __restrict__ xT)
{
    __shared__ float tile[64][65];
    int b = blockIdx.z, n0 = blockIdx.y * 64, c0 = blockIdx.x * 64;
    int lane = threadIdx.x & 63, wv = threadIdx.x >> 6;
    int n = n0 + lane;
    #pragma unroll
    for (int q = 0; q < 16; ++q) {
        int cc = wv * 16 + q;
        tile[cc][lane] = (n < 400) ? x[((long)b * 1024 + c0 + cc) * 400 + n] : 0.f;
    }
    __syncthreads();
    #pragma unroll
    for (int q = 0; q < 16; ++q) {
        int nn = wv * 16 + q;
        if (n0 + nn < 400)
            xT[((long)b * 400 + n0 + nn) * 1024 + c0 + lane] = tile[lane][nn];
    }
}

// ---------------- weight prep: pad + posk-permute + optional hi/lo split along K ----------------
__global__ void prep_w(const float* __restrict__ src, int R0, int K0,
                       unsigned short* __restrict__ dst, int K2, int khalf)
{
    int k = blockIdx.x * 256 + threadIdx.x;
    if (k >= K2) return;
    int r = blockIdx.y;
    int ks = k, half = 0;
    if (khalf && k >= khalf) { ks = k - khalf; half = 1; }
    float v = 0.f;
    if (r < R0 && ks < K0) v = src[(long)r * K0 + ks];
    unsigned short out;
    if (!khalf) out = f2bf(v);
    else {
        float hi = bf2f(f2bf(v));
        out = half ? f2bf(v - hi) : f2bf(hi);
    }
    dst[(long)r * K2 + posk(k)] = out;
}

// ---------------- param prep ----------------
__global__ void prep_params(
    const float* __restrict__ b1, const float* __restrict__ b2,
    const float* __restrict__ c1b, const float* __restrict__ g1, const float* __restrict__ bb1,
    const float* __restrict__ m1, const float* __restrict__ v1,
    const float* __restrict__ c2b, const float* __restrict__ g2, const float* __restrict__ bb2,
    const float* __restrict__ m2, const float* __restrict__ v2,
    float* __restrict__ b1p, float* __restrict__ b2p,
    float* __restrict__ sc1, float* __restrict__ sh1,
    float* __restrict__ sc2, float* __restrict__ sh2)
{
    int t = threadIdx.x;
    if (t < 512) {
        b1p[t] = (t < 400) ? b1[t] : 0.f;
        b2p[t] = (t < 400) ? b2[t] : 0.f;
        float sc = 0.f, sh = 0.f;
        if (t < 400) { sc = g1[t] / sqrtf(v1[t] + LN_EPS); sh = (c1b[t] - m1[t]) * sc + bb1[t]; }
        sc1[t] = sc; sh1[t] = sh;
    }
    float sc = g2[t] / sqrtf(v2[t] + LN_EPS);
    sc2[t] = sc;
    sh2[t] = (c2b[t] - m2[t]) * sc + bb2[t];
}

// ---------------- LIF1: LDS-staged scan over xT[b][n][c] -> s[(n*64+b)][posk(c)] ----------
// grid (8,64), 128 threads. Chunk = 40 timesteps x 128 channels staged via global_load_lds.
__global__ __launch_bounds__(128) void lif1(const float* __restrict__ xT, unsigned short* __restrict__ s)
{
    __shared__ float buf[40][128];
    const int tid = threadIdx.x;
    const int lane = tid & 63, w = tid >> 6;
    const int c0 = blockIdx.x * 128, b = blockIdx.y;
    const int pc = posk(c0 + tid);
    const int rsub = lane >> 5;            // row within 1KB issue
    const int koff = (lane & 31) << 2;     // f32 index within 512B row chunk
    float v = 0.f;
    for (int n0 = 0; n0 < 400; n0 += 40) {
        #pragma unroll
        for (int g = 0; g < 10; ++g) {
            int r = w * 20 + g * 2;
            const float* src = xT + ((long)b * 400 + n0 + r + rsub) * 1024 + c0 + koff;
            async16(src, &buf[r][0]);
        }
        __syncthreads();
        #pragma unroll 8
        for (int r = 0; r < 40; ++r) {
            float cur = buf[r][tid];
            v += (cur - v) * 0.5f;
            bool sk = (v >= 1.0f);
            s[((long)(n0 + r) * 64 + b) * 1024 + pc] = sk ? (unsigned short)0x3F80 : (unsigned short)0;
            if (sk) v = 0.f;
        }
        __syncthreads();
    }
}

// ---------------- LIF2: LDS-staged scan over y[(n*64+b)][o] -> s2[(n*64+b)][posk(o)] ----------
__global__ __launch_bounds__(128) void lif2(const float* __restrict__ y, unsigned short* __restrict__ s2)
{
    __shared__ float buf[40][128];
    const int tid = threadIdx.x;
    const int lane = tid & 63, w = tid >> 6;
    const int o0 = blockIdx.x * 128, b = blockIdx.y;
    const int o = o0 + tid;
    const int pco = (o < 448) ? posk(o) : 0;
    const int rsub = lane >> 5;
    const int koff = (lane & 31) << 2;
    float v = 0.f;
    for (int n0 = 0; n0 < 400; n0 += 40) {
        #pragma unroll
        for (int g = 0; g < 10; ++g) {
            int r = w * 20 + g * 2;
            const float* src = y + ((long)(n0 + r + rsub) * 64 + b) * 512 + o0 + koff;
            async16(src, &buf[r][0]);
        }
        __syncthreads();
        #pragma unroll 8
        for (int r = 0; r < 40; ++r) {
            float cur = buf[r][tid];
            v += (cur - v) * 0.5f;
            bool sk = (v >= 1.0f);
            if (o < 448)
                s2[((long)(n0 + r) * 64 + b) * 448 + pco] = sk ? (unsigned short)0x3F80 : (unsigned short)0;
            if (sk) v = 0.f;
        }
        __syncthreads();
    }
}

// ---------------- MFMA GEMM ----------------
template<int EPI>
__global__ __launch_bounds__(256) void mfma_gemm(
    const unsigned short* __restrict__ A, int ldA, long sAb,
    const unsigned short* __restrict__ B, int ldB,
    int KT, int wrapK,
    void* __restrict__ Cv,
    const float* __restrict__ p0, const float* __restrict__ p1)
{
    __shared__ char AsB[16384];
    __shared__ char BsB[16384];
    const int tid = threadIdx.x;
    const int lane = tid & 63, wid = tid >> 6;
    const int wm = wid >> 1, wn = wid & 1;
    const int m0 = blockIdx.y << 7, n0 = blockIdx.x << 7;
    const int bz = blockIdx.z;
    const unsigned short* Ab = A + (long)bz * sAb;

    const int srow = lane >> 3;
    const int koff = (lane & 7) << 4;
    const int ssw  = (srow & 7) << 4;

    f32x4 acc[4][4];
    #pragma unroll
    for (int i = 0; i < 4; ++i)
        #pragma unroll
        for (int j = 0; j < 4; ++j)
            acc[i][j] = (f32x4){0.f, 0.f, 0.f, 0.f};

    for (int kt = 0; kt < KT; ++kt) {
        int k0 = kt << 6;
        int k0a = (wrapK && k0 >= wrapK) ? (k0 - wrapK) : k0;
        __syncthreads();
        #pragma unroll
        for (int q = 0; q < 4; ++q) {
            int i = (wid << 2) + q;
            int row = (i << 3) + srow;
            const char* gA = (const char*)(Ab + (long)(m0 + row) * ldA + k0a) + (koff ^ ssw);
            async16(gA, AsB + (i << 10));
            const char* gB = (const char*)(B + (long)(n0 + row) * ldB + k0) + (koff ^ ssw);
            async16(gB, BsB + (i << 10));
        }
        __syncthreads();
        const int r16 = lane & 15;
        const int swl = (r16 & 7) << 4;
        #pragma unroll
        for (int kk = 0; kk < 2; ++kk) {
            int kb = (kk << 6) + ((lane >> 4) << 4);
            s8v af[4], bv[4];
            #pragma unroll
            for (int f = 0; f < 4; ++f) {
                int rowA = (wm << 6) + (f << 4) + r16;
                af[f] = *reinterpret_cast<const s8v*>(AsB + (rowA << 7) + (kb ^ swl));
                int rowB = (wn << 6) + (f << 4) + r16;
                bv[f] = *reinterpret_cast<const s8v*>(BsB + (rowB << 7) + (kb ^ swl));
            }
            #pragma unroll
            for (int fi = 0; fi < 4; ++fi)
                #pragma unroll
                for (int fj = 0; fj < 4; ++fj)
                    acc[fi][fj] = __builtin_amdgcn_mfma_f32_16x16x32_bf16(af[fi], bv[fj], acc[fi][fj], 0, 0, 0);
        }
    }

    const int r16 = lane & 15, g4 = (lane >> 4) << 2;
    unsigned short* hC = (unsigned short*)Cv;
    float* fC = (float*)Cv;
    #pragma unroll
    for (int fi = 0; fi < 4; ++fi) {
        #pragma unroll
        for (int fj = 0; fj < 4; ++fj) {
            int col = n0 + (wn << 6) + (fj << 4) + r16;
            int row0 = m0 + (wm << 6) + (fi << 4) + g4;
            f32x4 a = acc[fi][fj];
            if (EPI == 0) {
                if (col < 448) {
                    float bias = p0[col];
                    int pc = posk(col);
                    #pragma unroll
                    for (int r = 0; r < 4; ++r)
                        hC[(long)(row0 + r) * 448 + pc] = f2bf(fmaxf(a[r] + bias, 0.f));
                }
            } else if (EPI == 1) {
                int bb = col >> 10, cc = col & 1023;
                long rb = (long)bb * 409600;
                int pc = posk(cc);
                #pragma unroll
                for (int r = 0; r < 4; ++r) {
                    int row = row0 + r;
                    if (row < 400) {
                        float t = a[r] + p0[row] + p1[rb + (long)row * 1024 + cc];
                        hC[rb + (long)row * 1024 + pc] = f2bf(t);
                    }
                }
            } else if (EPI == 2) {
                float sc = p0[col], sh = p1[col];
                #pragma unroll
                for (int r = 0; r < 4; ++r)
                    fC[(long)(row0 + r) * 512 + col] = a[r] * sc + sh;
            } else if (EPI == 3) {
                float sc = p0[col], sh = p1[col];
                int pc = posk(col);
                #pragma unroll
                for (int r = 0; r < 4; ++r) {
                    int row = row0 + r;
                    int nn = row >> 6, bbb = row & 63;
                    long ad = ((long)bbb * 400 + nn) * 1024 + pc;
                    hC[ad] = f2bf(bf2f(hC[ad]) + a[r] * sc + sh);
                }
            } else {
                float bias = p0[col];
                #pragma unroll
                for (int r = 0; r < 4; ++r) {
                    int row = row0 + r;
                    if (row < 400)
                        fC[(long)bz * 204800 + (long)row * 512 + col] = a[r] + bias;
                }
            }
        }
    }
}

// ---------------- rp GEMM + L2 normalize ----------------
__global__ __launch_bounds__(512) void rp_norm(const float* __restrict__ xc,
        const float* __restrict__ rpw, const float* __restrict__ rpb,
        float* __restrict__ out)
{
    __shared__ float wr[1600];
    __shared__ float red[8];
    int b = blockIdx.x, o = threadIdx.x;
    for (int i = o; i < 1600; i += 512) wr[i] = rpw[i];
    __syncthreads();
    const float* xb = xc + (long)b * 204800 + o;
    float a0 = rpb[0], a1 = rpb[1], a2 = rpb[2], a3 = rpb[3];
    #pragma unroll 4
    for (int n = 0; n < 400; ++n) {
        float xv = xb[(long)n * 512];
        a0 = fmaf(xv, wr[n], a0);
        a1 = fmaf(xv, wr[400 + n], a1);
        a2 = fmaf(xv, wr[800 + n], a2);
        a3 = fmaf(xv, wr[1200 + n], a3);
    }
    float sq = a0*a0 + a1*a1 + a2*a2 + a3*a3;
    #pragma unroll
    for (int off2 = 32; off2; off2 >>= 1) sq += __shfl_down(sq, off2);
    if ((o & 63) == 0) red[o >> 6] = sq;
    __syncthreads();
    if (o == 0) {
        float t = 0.f;
        #pragma unroll
        for (int i = 0; i < 8; ++i) t += red[i];
        red[0] = fmaxf(sqrtf(t), 1e-12f);
    }
    __syncthreads();
    float inv = 1.f / red[0];
    float4 ov = make_float4(a0*inv, a1*inv, a2*inv, a3*inv);
    *reinterpret_cast<float4*>(out + (long)b * 2048 + o * 4) = ov;
}

extern "C" void kernel_launch(void* const* d_in, const int* in_sizes, int n_in,
                              void* d_out, int out_size, void* d_ws, size_t ws_size,
                              hipStream_t stream) {
    const float* x    = (const float*)d_in[0];
    const float* ln_g = (const float*)d_in[1];
    const float* ln_b = (const float*)d_in[2];
    const float* w1   = (const float*)d_in[3];
    const float* b1   = (const float*)d_in[4];
    const float* w2   = (const float*)d_in[5];
    const float* b2   = (const float*)d_in[6];
    const float* c1w  = (const float*)d_in[7];
    const float* c1b  = (const float*)d_in[8];
    const float* bn1g = (const float*)d_in[9];
    const float* bn1b = (const float*)d_in[10];
    const float* bn1m = (const float*)d_in[11];
    const float* bn1v = (const float*)d_in[12];
    const float* c2w  = (const float*)d_in[13];
    const float* c2b  = (const float*)d_in[14];
    const float* bn2g = (const float*)d_in[15];
    const float* bn2b = (const float*)d_in[16];
    const float* bn2m = (const float*)d_in[17];
    const float* bn2v = (const float*)d_in[18];
    const float* cpw  = (const float*)d_in[19];
    const float* cpb  = (const float*)d_in[20];
    const float* rpw  = (const float*)d_in[21];
    const float* rpb  = (const float*)d_in[22];

    char* ws = (char*)d_ws;
    size_t off = 0;
    auto alloc = [&](size_t n){ size_t o = off; off += (n + 255) & ~(size_t)255; return o; };

    unsigned short* regA = (unsigned short*)(ws + alloc(58720256));
    unsigned short* regB = (unsigned short*)(ws + alloc(58720256));
    char* regC = ws + alloc(104857600);

    unsigned short* xln  = regA;
    unsigned short* x1bf = regA;
    unsigned short* h1   = regB;
    unsigned short* s    = regB;
    float* xT = (float*)regC;
    float* y  = (float*)regC;
    unsigned short* s2 = (unsigned short*)(regC + 52428800);
    float* xc = (float*)regC;

    unsigned short* w1p  = (unsigned short*)(ws + alloc(458752));
    unsigned short* w2p  = (unsigned short*)(ws + alloc(458752));
    unsigned short* w1c  = (unsigned short*)(ws + alloc(2097152));
    unsigned short* w2c  = (unsigned short*)(ws + alloc(1835008));
    unsigned short* cpwp = (unsigned short*)(ws + alloc(1048576));
    float* b1p = (float*)(ws + alloc(2048));
    float* b2p = (float*)(ws + alloc(2048));
    float* sc1 = (float*)(ws + alloc(2048));
    float* sh1 = (float*)(ws + alloc(2048));
    float* sc2 = (float*)(ws + alloc(4096));
    float* sh2 = (float*)(ws + alloc(4096));

    prep_w<<<dim3(2, 512), 256, 0, stream>>>(w1, 400, 400, w1p, 448, 0);
    prep_w<<<dim3(2, 512), 256, 0, stream>>>(w2, 400, 400, w2p, 448, 0);
    prep_w<<<dim3(8, 512), 256, 0, stream>>>(c1w, 400, 1024, w1c, 2048, 1024);
    prep_w<<<dim3(4, 1024), 256, 0, stream>>>(c2w, 1024, 400, w2c, 896, 448);
    prep_w<<<dim3(4, 512), 256, 0, stream>>>(cpw, 512, 1024, cpwp, 1024, 0);
    prep_params<<<1, 1024, 0, stream>>>(b1, b2, c1b, bn1g, bn1b, bn1m, bn1v,
                                        c2b, bn2g, bn2b, bn2m, bn2v,
                                        b1p, b2p, sc1, sh1, sc2, sh2);

    // 1) LN(x) -> xln
    ln_fused<<<16384, 256, 0, stream>>>(x, ln_g, ln_b, xln);

    // 2) h1 = relu(xln @ w1p^T + b1)
    mfma_gemm<0><<<dim3(4, 512, 1), 256, 0, stream>>>(xln, 448, 0, w1p, 448, 7, 0, h1, b1p, nullptr);

    // 3) xT = transpose(x)
    transpose_x<<<dim3(16, 7, 64), 256, 0, stream>>>(x, xT);

    // 4) x1bf[b][n][c] = (h1 @ w2^T)^T + b2 + xT
    mfma_gemm<1><<<dim3(512, 4, 1), 256, 0, stream>>>(w2p, 448, 0, h1, 448, 7, 0, x1bf, b2p, xT);

    // 5) LIF1 (LDS-staged, reads xT): -> s
    lif1<<<dim3(8, 64), 128, 0, stream>>>(xT, s);

    // 6) conv1+bn1: y = bn1(s @ c1w^T)   [regC: xT dead after steps 4&5]
    mfma_gemm<2><<<dim3(4, 200, 1), 256, 0, stream>>>(s, 1024, 0, w1c, 2048, 32, 1024, y, sc1, sh1);

    // 7) LIF2 (LDS-staged): y -> s2
    lif2<<<dim3(4, 64), 128, 0, stream>>>(y, s2);

    // 8) conv2+bn2 (RMW into x1bf)
    mfma_gemm<3><<<dim3(8, 200, 1), 256, 0, stream>>>(s2, 448, 0, w2c, 896, 14, 448, x1bf, sc2, sh2);

    // 9) cp: xc[b][n][o] = x1bf[b] @ cpw^T + cpb
    mfma_gemm<4><<<dim3(4, 4, 64), 256, 0, stream>>>(x1bf, 1024, 409600, cpwp, 1024, 16, 0, xc, cpb, nullptr);

    // 10) rp + L2 normalize
    rp_norm<<<64, 512, 0, stream>>>(xc, rpw, rpb, (float*)d_out);
}

// Round 5
// 558.970 us; speedup vs baseline: 3.5094x; 1.0942x over previous
//
#include <hip/hip_runtime.h>
#include <hip/hip_bf16.h>

typedef __attribute__((ext_vector_type(8))) short s8v;
typedef __attribute__((ext_vector_type(4))) float f32x4;
using bf16 = __hip_bfloat16;

#define LN_EPS 1e-5f

__device__ __forceinline__ float bf2f(unsigned short b){ return __uint_as_float(((unsigned)b)<<16); }
__device__ __forceinline__ unsigned short f2bf(float f){ __hip_bfloat16 h = __float2bfloat16(f); return *reinterpret_cast<unsigned short*>(&h); }

// MFMA k-half permutation: stored position of true k within each 32-k block.
__device__ __forceinline__ int posk(int k){
    int q = (k >> 2) & 7;
    int s = (q < 4) ? (2*q) : (2*q - 7);
    return (k & ~31) | (s << 2) | (k & 3);
}

__device__ __forceinline__ void async16(const void* g, void* l){
    __builtin_amdgcn_global_load_lds(
        (const __attribute__((address_space(1))) unsigned int*)g,
        (__attribute__((address_space(3))) unsigned int*)l, 16, 0, 0);
}

// ---------------- fused LayerNorm -> padded+permuted bf16 A-matrix ----------------
__global__ __launch_bounds__(256) void ln_fused(const float* __restrict__ x,
        const float* __restrict__ g, const float* __restrict__ b,
        unsigned short* __restrict__ xln)
{
    int lane = threadIdx.x & 63, wv = threadIdx.x >> 6;
    long row = (long)blockIdx.x * 4 + wv;
    const float* xr = x + row * 400;
    float v[7];
    float s = 0.f, ss = 0.f;
    #pragma unroll
    for (int i = 0; i < 7; ++i) {
        int n = lane + i * 64;
        float t = (n < 400) ? xr[n] : 0.f;
        v[i] = t; s += t; ss += t * t;
    }
    #pragma unroll
    for (int o = 32; o; o >>= 1) { s += __shfl_down(s, o); ss += __shfl_down(ss, o); }
    s = __shfl(s, 0); ss = __shfl(ss, 0);
    float mu = s * 0.0025f;
    float rstd = rsqrtf(ss * 0.0025f - mu * mu + LN_EPS);
    unsigned short* orow = xln + row * 448;
    #pragma unroll
    for (int i = 0; i < 7; ++i) {
        int n = lane + i * 64;
        float t = (n < 400) ? ((v[i] - mu) * rstd * g[n] + b[n]) : 0.f;
        orow[posk(n)] = f2bf(t);
    }
}

// ---------------- x[b][c][n] -> xT[b][n][c] f32 ----------------
__global__ __launch_bounds__(256) void transpose_x(const float* __restrict__ x, float* __restrict__ xT)
{
    __shared__ float tile[64][65];
    int b = blockIdx.z, n0 = blockIdx.y * 64, c0 = blockIdx.x * 64;
    int lane = threadIdx.x & 63, wv = threadIdx.x >> 6;
    int n = n0 + lane;
    #pragma unroll
    for (int q = 0; q < 16; ++q) {
        int cc = wv * 16 + q;
        tile[cc][lane] = (n < 400) ? x[((long)b * 1024 + c0 + cc) * 400 + n] : 0.f;
    }
    __syncthreads();
    #pragma unroll
    for (int q = 0; q < 16; ++q) {
        int nn = wv * 16 + q;
        if (n0 + nn < 400)
            xT[((long)b * 400 + n0 + nn) * 1024 + c0 + lane] = tile[lane][nn];
    }
}

// ---------------- weight prep: pad + posk-permute + optional hi/lo split along K ----------------
__global__ void prep_w(const float* __restrict__ src, int R0, int K0,
                       unsigned short* __restrict__ dst, int K2, int khalf)
{
    int k = blockIdx.x * 256 + threadIdx.x;
    if (k >= K2) return;
    int r = blockIdx.y;
    int ks = k, half = 0;
    if (khalf && k >= khalf) { ks = k - khalf; half = 1; }
    float v = 0.f;
    if (r < R0 && ks < K0) v = src[(long)r * K0 + ks];
    unsigned short out;
    if (!khalf) out = f2bf(v);
    else {
        float hi = bf2f(f2bf(v));
        out = half ? f2bf(v - hi) : f2bf(hi);
    }
    dst[(long)r * K2 + posk(k)] = out;
}

// ---------------- param prep ----------------
__global__ void prep_params(
    const float* __restrict__ b1, const float* __restrict__ b2,
    const float* __restrict__ c1b, const float* __restrict__ g1, const float* __restrict__ bb1,
    const float* __restrict__ m1, const float* __restrict__ v1,
    const float* __restrict__ c2b, const float* __restrict__ g2, const float* __restrict__ bb2,
    const float* __restrict__ m2, const float* __restrict__ v2,
    float* __restrict__ b1p, float* __restrict__ b2p,
    float* __restrict__ sc1, float* __restrict__ sh1,
    float* __restrict__ sc2, float* __restrict__ sh2)
{
    int t = threadIdx.x;
    if (t < 512) {
        b1p[t] = (t < 400) ? b1[t] : 0.f;
        b2p[t] = (t < 400) ? b2[t] : 0.f;
        float sc = 0.f, sh = 0.f;
        if (t < 400) { sc = g1[t] / sqrtf(v1[t] + LN_EPS); sh = (c1b[t] - m1[t]) * sc + bb1[t]; }
        sc1[t] = sc; sh1[t] = sh;
    }
    float sc = g2[t] / sqrtf(v2[t] + LN_EPS);
    sc2[t] = sc;
    sh2[t] = (c2b[t] - m2[t]) * sc + bb2[t];
}

// ---------------- LIF1: LDS-staged scan over xT[b][n][c] -> s[(n*64+b)][posk(c)] ----------
__global__ __launch_bounds__(128) void lif1(const float* __restrict__ xT, unsigned short* __restrict__ s)
{
    __shared__ float buf[40][128];
    const int tid = threadIdx.x;
    const int lane = tid & 63, w = tid >> 6;
    const int c0 = blockIdx.x * 128, b = blockIdx.y;
    const int pc = posk(c0 + tid);
    const int rsub = lane >> 5;
    const int koff = (lane & 31) << 2;
    float v = 0.f;
    for (int n0 = 0; n0 < 400; n0 += 40) {
        #pragma unroll
        for (int g = 0; g < 10; ++g) {
            int r = w * 20 + g * 2;
            const float* src = xT + ((long)b * 400 + n0 + r + rsub) * 1024 + c0 + koff;
            async16(src, &buf[r][0]);
        }
        __syncthreads();
        #pragma unroll 8
        for (int r = 0; r < 40; ++r) {
            float cur = buf[r][tid];
            v += (cur - v) * 0.5f;
            bool sk = (v >= 1.0f);
            s[((long)(n0 + r) * 64 + b) * 1024 + pc] = sk ? (unsigned short)0x3F80 : (unsigned short)0;
            if (sk) v = 0.f;
        }
        __syncthreads();
    }
}

// ---------------- LIF2: LDS-staged scan over y[(n*64+b)][o] -> s2[(n*64+b)][posk(o)] ----------
__global__ __launch_bounds__(128) void lif2(const float* __restrict__ y, unsigned short* __restrict__ s2)
{
    __shared__ float buf[40][128];
    const int tid = threadIdx.x;
    const int lane = tid & 63, w = tid >> 6;
    const int o0 = blockIdx.x * 128, b = blockIdx.y;
    const int o = o0 + tid;
    const int pco = (o < 448) ? posk(o) : 0;
    const int rsub = lane >> 5;
    const int koff = (lane & 31) << 2;
    float v = 0.f;
    for (int n0 = 0; n0 < 400; n0 += 40) {
        #pragma unroll
        for (int g = 0; g < 10; ++g) {
            int r = w * 20 + g * 2;
            const float* src = y + ((long)(n0 + r + rsub) * 64 + b) * 512 + o0 + koff;
            async16(src, &buf[r][0]);
        }
        __syncthreads();
        #pragma unroll 8
        for (int r = 0; r < 40; ++r) {
            float cur = buf[r][tid];
            v += (cur - v) * 0.5f;
            bool sk = (v >= 1.0f);
            if (o < 448)
                s2[((long)(n0 + r) * 64 + b) * 448 + pco] = sk ? (unsigned short)0x3F80 : (unsigned short)0;
            if (sk) v = 0.f;
        }
        __syncthreads();
    }
}

// ---------------- MFMA GEMM: D[m][n] = sum_k A[m][k]*B[n][k], 2-phase dbuf pipeline ----------
// GMODE 0: n0=bx, m0=by | 1: m0=bx, n0=by (A-panel sharers land on same XCD) |
//       2: 1-D grid, b fastest: id=(n*4+m)*64+b (cp)
template<int EPI, int GMODE>
__global__ __launch_bounds__(256) void mfma_gemm(
    const unsigned short* __restrict__ A, int ldA, long sAb,
    const unsigned short* __restrict__ B, int ldB,
    int KT, int wrapK,
    void* __restrict__ Cv,
    const float* __restrict__ p0, const float* __restrict__ p1)
{
    __shared__ char LDS[2][32768];   // [buf][A 16KB | B 16KB]
    const int tid = threadIdx.x;
    const int lane = tid & 63, wid = tid >> 6;
    const int wm = wid >> 1, wn = wid & 1;
    int m0, n0, bz;
    if (GMODE == 2) {
        int id = blockIdx.x;
        bz = id & 63;
        int mn = id >> 6;
        m0 = (mn & 3) << 7;
        n0 = (mn >> 2) << 7;
    } else if (GMODE == 1) {
        m0 = blockIdx.x << 7; n0 = blockIdx.y << 7; bz = blockIdx.z;
    } else {
        n0 = blockIdx.x << 7; m0 = blockIdx.y << 7; bz = blockIdx.z;
    }
    const unsigned short* Ab = A + (long)bz * sAb;

    const int srow = lane >> 3;
    const int koff = (lane & 7) << 4;
    const int ssw  = (srow & 7) << 4;

    f32x4 acc[4][4];
    #pragma unroll
    for (int i = 0; i < 4; ++i)
        #pragma unroll
        for (int j = 0; j < 4; ++j)
            acc[i][j] = (f32x4){0.f, 0.f, 0.f, 0.f};

    auto stage = [&](char* dst, int kt){
        int k0 = kt << 6;
        int k0a = (wrapK && k0 >= wrapK) ? (k0 - wrapK) : k0;
        #pragma unroll
        for (int q = 0; q < 4; ++q) {
            int i = (wid << 2) + q;
            int row = (i << 3) + srow;
            const char* gA = (const char*)(Ab + (long)(m0 + row) * ldA + k0a) + (koff ^ ssw);
            async16(gA, dst + (i << 10));
            const char* gB = (const char*)(B + (long)(n0 + row) * ldB + k0) + (koff ^ ssw);
            async16(gB, dst + 16384 + (i << 10));
        }
    };

    stage(LDS[0], 0);
    __syncthreads();

    const int r16 = lane & 15;
    const int swl = (r16 & 7) << 4;
    int cur = 0;
    for (int kt = 0; kt < KT; ++kt) {
        if (kt + 1 < KT) stage(LDS[cur ^ 1], kt + 1);   // prefetch next tile (overlaps MFMA below)
        const char* AsB = LDS[cur];
        const char* BsB = LDS[cur] + 16384;
        #pragma unroll
        for (int kk = 0; kk < 2; ++kk) {
            int kb = (kk << 6) + ((lane >> 4) << 4);
            s8v af[4], bv[4];
            #pragma unroll
            for (int f = 0; f < 4; ++f) {
                int rowA = (wm << 6) + (f << 4) + r16;
                af[f] = *reinterpret_cast<const s8v*>(AsB + (rowA << 7) + (kb ^ swl));
                int rowB = (wn << 6) + (f << 4) + r16;
                bv[f] = *reinterpret_cast<const s8v*>(BsB + (rowB << 7) + (kb ^ swl));
            }
            #pragma unroll
            for (int fi = 0; fi < 4; ++fi)
                #pragma unroll
                for (int fj = 0; fj < 4; ++fj)
                    acc[fi][fj] = __builtin_amdgcn_mfma_f32_16x16x32_bf16(af[fi], bv[fj], acc[fi][fj], 0, 0, 0);
        }
        __syncthreads();   // vmcnt(0)+lgkmcnt(0)+barrier: next buf ready, cur buf free
        cur ^= 1;
    }

    const int g4 = (lane >> 4) << 2;
    unsigned short* hC = (unsigned short*)Cv;
    float* fC = (float*)Cv;
    #pragma unroll
    for (int fi = 0; fi < 4; ++fi) {
        #pragma unroll
        for (int fj = 0; fj < 4; ++fj) {
            int col = n0 + (wn << 6) + (fj << 4) + r16;
            int row0 = m0 + (wm << 6) + (fi << 4) + g4;
            f32x4 a = acc[fi][fj];
            if (EPI == 0) {
                if (col < 448) {
                    float bias = p0[col];
                    int pc = posk(col);
                    #pragma unroll
                    for (int r = 0; r < 4; ++r)
                        hC[(long)(row0 + r) * 448 + pc] = f2bf(fmaxf(a[r] + bias, 0.f));
                }
            } else if (EPI == 1) {
                int bb = col >> 10, cc = col & 1023;
                long rb = (long)bb * 409600;
                int pc = posk(cc);
                #pragma unroll
                for (int r = 0; r < 4; ++r) {
                    int row = row0 + r;
                    if (row < 400) {
                        float t = a[r] + p0[row] + p1[rb + (long)row * 1024 + cc];
                        hC[rb + (long)row * 1024 + pc] = f2bf(t);
                    }
                }
            } else if (EPI == 2) {
                float sc = p0[col], sh = p1[col];
                #pragma unroll
                for (int r = 0; r < 4; ++r)
                    fC[(long)(row0 + r) * 512 + col] = a[r] * sc + sh;
            } else if (EPI == 3) {
                float sc = p0[col], sh = p1[col];
                int pc = posk(col);
                #pragma unroll
                for (int r = 0; r < 4; ++r) {
                    int row = row0 + r;
                    int nn = row >> 6, bbb = row & 63;
                    long ad = ((long)bbb * 400 + nn) * 1024 + pc;
                    hC[ad] = f2bf(bf2f(hC[ad]) + a[r] * sc + sh);
                }
            } else {
                float bias = p0[col];
                #pragma unroll
                for (int r = 0; r < 4; ++r) {
                    int row = row0 + r;
                    if (row < 400)
                        fC[(long)bz * 204800 + (long)row * 512 + col] = a[r] + bias;
                }
            }
        }
    }
}

// ---------------- rp GEMM + L2 normalize ----------------
__global__ __launch_bounds__(512) void rp_norm(const float* __restrict__ xc,
        const float* __restrict__ rpw, const float* __restrict__ rpb,
        float* __restrict__ out)
{
    __shared__ float wr[1600];
    __shared__ float red[8];
    int b = blockIdx.x, o = threadIdx.x;
    for (int i = o; i < 1600; i += 512) wr[i] = rpw[i];
    __syncthreads();
    const float* xb = xc + (long)b * 204800 + o;
    float a0 = rpb[0], a1 = rpb[1], a2 = rpb[2], a3 = rpb[3];
    #pragma unroll 4
    for (int n = 0; n < 400; ++n) {
        float xv = xb[(long)n * 512];
        a0 = fmaf(xv, wr[n], a0);
        a1 = fmaf(xv, wr[400 + n], a1);
        a2 = fmaf(xv, wr[800 + n], a2);
        a3 = fmaf(xv, wr[1200 + n], a3);
    }
    float sq = a0*a0 + a1*a1 + a2*a2 + a3*a3;
    #pragma unroll
    for (int off2 = 32; off2; off2 >>= 1) sq += __shfl_down(sq, off2);
    if ((o & 63) == 0) red[o >> 6] = sq;
    __syncthreads();
    if (o == 0) {
        float t = 0.f;
        #pragma unroll
        for (int i = 0; i < 8; ++i) t += red[i];
        red[0] = fmaxf(sqrtf(t), 1e-12f);
    }
    __syncthreads();
    float inv = 1.f / red[0];
    float4 ov = make_float4(a0*inv, a1*inv, a2*inv, a3*inv);
    *reinterpret_cast<float4*>(out + (long)b * 2048 + o * 4) = ov;
}

extern "C" void kernel_launch(void* const* d_in, const int* in_sizes, int n_in,
                              void* d_out, int out_size, void* d_ws, size_t ws_size,
                              hipStream_t stream) {
    const float* x    = (const float*)d_in[0];
    const float* ln_g = (const float*)d_in[1];
    const float* ln_b = (const float*)d_in[2];
    const float* w1   = (const float*)d_in[3];
    const float* b1   = (const float*)d_in[4];
    const float* w2   = (const float*)d_in[5];
    const float* b2   = (const float*)d_in[6];
    const float* c1w  = (const float*)d_in[7];
    const float* c1b  = (const float*)d_in[8];
    const float* bn1g = (const float*)d_in[9];
    const float* bn1b = (const float*)d_in[10];
    const float* bn1m = (const float*)d_in[11];
    const float* bn1v = (const float*)d_in[12];
    const float* c2w  = (const float*)d_in[13];
    const float* c2b  = (const float*)d_in[14];
    const float* bn2g = (const float*)d_in[15];
    const float* bn2b = (const float*)d_in[16];
    const float* bn2m = (const float*)d_in[17];
    const float* bn2v = (const float*)d_in[18];
    const float* cpw  = (const float*)d_in[19];
    const float* cpb  = (const float*)d_in[20];
    const float* rpw  = (const float*)d_in[21];
    const float* rpb  = (const float*)d_in[22];

    char* ws = (char*)d_ws;
    size_t off = 0;
    auto alloc = [&](size_t n){ size_t o = off; off += (n + 255) & ~(size_t)255; return o; };

    unsigned short* regA = (unsigned short*)(ws + alloc(58720256));
    unsigned short* regB = (unsigned short*)(ws + alloc(58720256));
    char* regC = ws + alloc(104857600);

    unsigned short* xln  = regA;
    unsigned short* x1bf = regA;
    unsigned short* h1   = regB;
    unsigned short* s    = regB;
    float* xT = (float*)regC;
    float* y  = (float*)regC;
    unsigned short* s2 = (unsigned short*)(regC + 52428800);
    float* xc = (float*)regC;

    unsigned short* w1p  = (unsigned short*)(ws + alloc(458752));
    unsigned short* w2p  = (unsigned short*)(ws + alloc(458752));
    unsigned short* w1c  = (unsigned short*)(ws + alloc(2097152));  // [512][2048] hi|lo
    unsigned short* w2c  = (unsigned short*)(ws + alloc(1835008));  // [1024][448] (no split now)
    unsigned short* cpwp = (unsigned short*)(ws + alloc(1048576));
    float* b1p = (float*)(ws + alloc(2048));
    float* b2p = (float*)(ws + alloc(2048));
    float* sc1 = (float*)(ws + alloc(2048));
    float* sh1 = (float*)(ws + alloc(2048));
    float* sc2 = (float*)(ws + alloc(4096));
    float* sh2 = (float*)(ws + alloc(4096));

    prep_w<<<dim3(2, 512), 256, 0, stream>>>(w1, 400, 400, w1p, 448, 0);
    prep_w<<<dim3(2, 512), 256, 0, stream>>>(w2, 400, 400, w2p, 448, 0);
    prep_w<<<dim3(8, 512), 256, 0, stream>>>(c1w, 400, 1024, w1c, 2048, 1024);
    prep_w<<<dim3(2, 1024), 256, 0, stream>>>(c2w, 1024, 400, w2c, 448, 0);
    prep_w<<<dim3(4, 512), 256, 0, stream>>>(cpw, 512, 1024, cpwp, 1024, 0);
    prep_params<<<1, 1024, 0, stream>>>(b1, b2, c1b, bn1g, bn1b, bn1m, bn1v,
                                        c2b, bn2g, bn2b, bn2m, bn2v,
                                        b1p, b2p, sc1, sh1, sc2, sh2);

    // 1) LN(x) -> xln
    ln_fused<<<16384, 256, 0, stream>>>(x, ln_g, ln_b, xln);

    // 2) h1 = relu(xln @ w1p^T + b1)   [GMODE1: A-sharers stride 512 -> same XCD]
    mfma_gemm<0,1><<<dim3(512, 4, 1), 256, 0, stream>>>(xln, 448, 0, w1p, 448, 7, 0, h1, b1p, nullptr);

    // 3) xT = transpose(x)
    transpose_x<<<dim3(16, 7, 64), 256, 0, stream>>>(x, xT);

    // 4) x1bf[b][n][c] = (h1 @ w2^T)^T + b2 + xT   [GMODE0: B-sharers stride 512 -> same XCD]
    mfma_gemm<1,0><<<dim3(512, 4, 1), 256, 0, stream>>>(w2p, 448, 0, h1, 448, 7, 0, x1bf, b2p, xT);

    // 5) LIF1 (LDS-staged, reads xT): -> s
    lif1<<<dim3(8, 64), 128, 0, stream>>>(xT, s);

    // 6) conv1+bn1 (hi/lo split, K=2048 wrap 1024)  [GMODE1: s-sharers stride 200 -> same XCD]
    mfma_gemm<2,1><<<dim3(200, 4, 1), 256, 0, stream>>>(s, 1024, 0, w1c, 2048, 32, 1024, y, sc1, sh1);

    // 7) LIF2 (LDS-staged): y -> s2
    lif2<<<dim3(4, 64), 128, 0, stream>>>(y, s2);

    // 8) conv2+bn2 (single bf16, K=448; RMW into x1bf)  [GMODE1]
    mfma_gemm<3,1><<<dim3(200, 8, 1), 256, 0, stream>>>(s2, 448, 0, w2c, 448, 7, 0, x1bf, sc2, sh2);

    // 9) cp: xc[b][n][o] = x1bf[b] @ cpw^T + cpb  [GMODE2: 1-D grid, A-sharers stride 256]
    mfma_gemm<4,2><<<dim3(1024), 256, 0, stream>>>(x1bf, 1024, 409600, cpwp, 1024, 16, 0, xc, cpb, nullptr);

    // 10) rp + L2 normalize
    rp_norm<<<64, 512, 0, stream>>>(xc, rpw, rpb, (float*)d_out);
}